// Round 1
// baseline (1377.902 us; speedup 1.0000x reference)
//
#include <hip/hip_runtime.h>

// ---------------------------------------------------------------------------
// GCN: 4x GCNConv(128->128) + final linear. fp32 end-to-end.
// Strategy: build CSR (by destination col) once per call in d_ws, then per
// layer: dense GEMM (t = h @ W) and CSR gather-aggregate
// (out[c] = sum norm*t[src] + t[c]*disq[c]^2 + b, relu).
// d_out is reused as the GEMM scratch "t" for all but the final GEMM.
// ---------------------------------------------------------------------------

__global__ __launch_bounds__(256) void k_init(float* deg, int* count, int n) {
    int i = blockIdx.x * 256 + threadIdx.x;
    if (i < n) { deg[i] = 1.0f; count[i] = 0; }   // self-loop weight 1
}

__global__ __launch_bounds__(256) void k_count(const int* __restrict__ col,
                                               const float* __restrict__ ew,
                                               float* deg, int* count, int E) {
    int e = blockIdx.x * 256 + threadIdx.x;
    if (e < E) {
        int c = col[e];
        atomicAdd(&deg[c], ew[e]);
        atomicAdd(&count[c], 1);
    }
}

__global__ __launch_bounds__(256) void k_disq(const float* __restrict__ deg,
                                              float* disq, int n) {
    int i = blockIdx.x * 256 + threadIdx.x;
    if (i < n) disq[i] = 1.0f / sqrtf(deg[i]);    // deg >= 1 always
}

// Single-block exclusive prefix sum over n counts (n <= 1024*chunk).
__global__ __launch_bounds__(1024) void k_scan(const int* __restrict__ count,
                                               int* __restrict__ offsets,
                                               int* __restrict__ cursor, int n) {
    __shared__ int sums[1024];
    int t = threadIdx.x;
    int C = (n + 1023) >> 10;
    int begin = t * C;
    int end = min(begin + C, n);
    int s = 0;
    for (int i = begin; i < end; i++) s += count[i];
    sums[t] = s;
    __syncthreads();
    for (int off = 1; off < 1024; off <<= 1) {
        int v = (t >= off) ? sums[t - off] : 0;
        __syncthreads();
        sums[t] += v;
        __syncthreads();
    }
    int run = (t == 0) ? 0 : sums[t - 1];
    for (int i = begin; i < end; i++) {
        offsets[i] = run;
        cursor[i]  = run;
        run += count[i];
    }
    if (t == 1023) offsets[n] = sums[1023];
}

__global__ __launch_bounds__(256) void k_fill(const int* __restrict__ row,
                                              const int* __restrict__ col,
                                              const float* __restrict__ ew,
                                              const float* __restrict__ disq,
                                              int* cursor, int* __restrict__ srcs,
                                              float* __restrict__ norms, int E) {
    int e = blockIdx.x * 256 + threadIdx.x;
    if (e < E) {
        int c = col[e], r = row[e];
        int slot = atomicAdd(&cursor[c], 1);
        srcs[slot]  = r;
        norms[slot] = disq[r] * ew[e] * disq[c];
    }
}

// C = A @ W (+ bias). A: N x 128, W: 128 x 128 row-major. 128x128 block tile,
// 8x8 per-thread register tile, KB=32 LDS staging.
__global__ __launch_bounds__(256) void k_gemm128(const float* __restrict__ A,
                                                 const float* __restrict__ W,
                                                 const float* __restrict__ bias,
                                                 float* __restrict__ C, int N) {
    __shared__ float As[32][132];   // [k][row], pad 132 to soften store conflicts
    __shared__ float Ws[32][128];   // [k][col]
    int tid = threadIdx.x;
    int tx = tid & 15, ty = tid >> 4;
    int rowBase = blockIdx.x * 128;

    float acc[8][8];
#pragma unroll
    for (int i = 0; i < 8; i++)
#pragma unroll
        for (int j = 0; j < 8; j++) acc[i][j] = 0.0f;

    for (int ks = 0; ks < 128; ks += 32) {
        // Stage A: 128 rows x 32 k; each thread 4x float4, store transposed.
#pragma unroll
        for (int i = 0; i < 4; i++) {
            int lin = tid + i * 256;        // 0..1023
            int r   = lin >> 3;             // 0..127
            int kq  = (lin & 7) << 2;       // 0,4,...,28
            int gr  = rowBase + r;
            float4 v = make_float4(0.f, 0.f, 0.f, 0.f);
            if (gr < N) v = *(const float4*)&A[gr * 128 + ks + kq];
            As[kq + 0][r] = v.x;
            As[kq + 1][r] = v.y;
            As[kq + 2][r] = v.z;
            As[kq + 3][r] = v.w;
        }
        // Stage W: 32 k x 128 cols, layout-preserving.
#pragma unroll
        for (int i = 0; i < 4; i++) {
            int lin = tid + i * 256;
            int k   = lin >> 5;             // 0..31
            int cq  = (lin & 31) << 2;      // 0..124
            *(float4*)&Ws[k][cq] = *(const float4*)&W[(ks + k) * 128 + cq];
        }
        __syncthreads();
#pragma unroll
        for (int k = 0; k < 32; k++) {
            float4 a0 = *(const float4*)&As[k][ty * 8];
            float4 a1 = *(const float4*)&As[k][ty * 8 + 4];
            float4 b0 = *(const float4*)&Ws[k][tx * 8];
            float4 b1 = *(const float4*)&Ws[k][tx * 8 + 4];
            float a[8] = {a0.x, a0.y, a0.z, a0.w, a1.x, a1.y, a1.z, a1.w};
            float b[8] = {b0.x, b0.y, b0.z, b0.w, b1.x, b1.y, b1.z, b1.w};
#pragma unroll
            for (int i = 0; i < 8; i++)
#pragma unroll
                for (int j = 0; j < 8; j++) acc[i][j] += a[i] * b[j];
        }
        __syncthreads();
    }
#pragma unroll
    for (int i = 0; i < 8; i++) {
        int gr = rowBase + ty * 8 + i;
        if (gr < N) {
#pragma unroll
            for (int jq = 0; jq < 2; jq++) {
                int c0 = tx * 8 + jq * 4;
                float4 v;
                v.x = acc[i][jq * 4 + 0];
                v.y = acc[i][jq * 4 + 1];
                v.z = acc[i][jq * 4 + 2];
                v.w = acc[i][jq * 4 + 3];
                if (bias) {
                    v.x += bias[c0 + 0];
                    v.y += bias[c0 + 1];
                    v.z += bias[c0 + 2];
                    v.w += bias[c0 + 3];
                }
                *(float4*)&C[gr * 128 + c0] = v;
            }
        }
    }
}

// One wave (64 lanes) per node; lane handles 2 features (float2).
// out[c] = sum_e norm[e]*t[src[e]] + t[c]*disq[c]^2 + bias ; optional relu.
__global__ __launch_bounds__(256) void k_aggregate(const float* __restrict__ t,
                                                   const int* __restrict__ offsets,
                                                   const int* __restrict__ srcs,
                                                   const float* __restrict__ norms,
                                                   const float* __restrict__ disq,
                                                   const float* __restrict__ bias,
                                                   float* __restrict__ out,
                                                   int N, int relu) {
    int wave = threadIdx.x >> 6;
    int lane = threadIdx.x & 63;
    int node = blockIdx.x * 4 + wave;
    if (node >= N) return;

    float d = disq[node];
    float2 tv = *(const float2*)&t[node * 128 + 2 * lane];
    float2 bv = *(const float2*)&bias[2 * lane];
    float ax = tv.x * d * d + bv.x;
    float ay = tv.y * d * d + bv.y;

    int e0 = offsets[node], e1 = offsets[node + 1];
    for (int eb = e0; eb < e1; eb += 64) {
        int n_e = min(64, e1 - eb);
        int   src_l  = 0;
        float norm_l = 0.f;
        if (lane < n_e) {
            src_l  = srcs[eb + lane];
            norm_l = norms[eb + lane];
        }
        int i = 0;
        for (; i + 2 <= n_e; i += 2) {
            int   s0 = __shfl(src_l, i);
            int   s1 = __shfl(src_l, i + 1);
            float n0 = __shfl(norm_l, i);
            float n1 = __shfl(norm_l, i + 1);
            float2 h0 = *(const float2*)&t[s0 * 128 + 2 * lane];
            float2 h1 = *(const float2*)&t[s1 * 128 + 2 * lane];
            ax += n0 * h0.x + n1 * h1.x;
            ay += n0 * h0.y + n1 * h1.y;
        }
        if (i < n_e) {
            int   s0 = __shfl(src_l, i);
            float n0 = __shfl(norm_l, i);
            float2 h0 = *(const float2*)&t[s0 * 128 + 2 * lane];
            ax += n0 * h0.x;
            ay += n0 * h0.y;
        }
    }
    if (relu) { ax = fmaxf(ax, 0.f); ay = fmaxf(ay, 0.f); }
    float2 o; o.x = ax; o.y = ay;
    *(float2*)&out[node * 128 + 2 * lane] = o;
}

extern "C" void kernel_launch(void* const* d_in, const int* in_sizes, int n_in,
                              void* d_out, int out_size, void* d_ws, size_t ws_size,
                              hipStream_t stream) {
    const float* x    = (const float*)d_in[0];
    const int*   ei   = (const int*)d_in[1];
    const float* ew   = (const float*)d_in[2];
    const float* Wc[4] = {(const float*)d_in[3], (const float*)d_in[5],
                          (const float*)d_in[7], (const float*)d_in[9]};
    const float* bc[4] = {(const float*)d_in[4], (const float*)d_in[6],
                          (const float*)d_in[8], (const float*)d_in[10]};
    const float* Wout = (const float*)d_in[11];
    const float* bout = (const float*)d_in[12];

    const int N = in_sizes[0] / 128;
    const int E = in_sizes[2];
    const int* row = ei;        // edge_index[0]
    const int* col = ei + E;    // edge_index[1]

    // Workspace bump allocator (256B aligned regions).
    size_t off = 0;
    char* base = (char*)d_ws;
    auto alloc = [&](size_t bytes) -> void* {
        void* p = base + off;
        off += (bytes + 255) & ~(size_t)255;
        return p;
    };
    float* deg     = (float*)alloc((size_t)N * 4);
    float* disq    = (float*)alloc((size_t)N * 4);
    int*   count   = (int*)alloc((size_t)N * 4);
    int*   offsets = (int*)alloc((size_t)(N + 1) * 4);
    int*   cursor  = (int*)alloc((size_t)N * 4);
    int*   srcs    = (int*)alloc((size_t)E * 4);
    float* norms   = (float*)alloc((size_t)E * 4);
    float* hA      = (float*)alloc((size_t)N * 128 * 4);
    float* hB      = (float*)alloc((size_t)N * 128 * 4);
    float* t       = (float*)d_out;   // GEMM scratch; overwritten by final GEMM

    const int BN = (N + 255) / 256;
    const int BE = (E + 255) / 256;
    const int BG = (N + 127) / 128;
    const int BA = (N + 3) / 4;

    // CSR build
    k_init<<<BN, 256, 0, stream>>>(deg, count, N);
    k_count<<<BE, 256, 0, stream>>>(col, ew, deg, count, E);
    k_disq<<<BN, 256, 0, stream>>>(deg, disq, N);
    k_scan<<<1, 1024, 0, stream>>>(count, offsets, cursor, N);
    k_fill<<<BE, 256, 0, stream>>>(row, col, ew, disq, cursor, srcs, norms, E);

    // Layer 0: x -> hA
    k_gemm128<<<BG, 256, 0, stream>>>(x, Wc[0], nullptr, t, N);
    k_aggregate<<<BA, 256, 0, stream>>>(t, offsets, srcs, norms, disq, bc[0], hA, N, 1);
    // Layer 1: hA -> hB
    k_gemm128<<<BG, 256, 0, stream>>>(hA, Wc[1], nullptr, t, N);
    k_aggregate<<<BA, 256, 0, stream>>>(t, offsets, srcs, norms, disq, bc[1], hB, N, 1);
    // Layer 2: hB -> hA
    k_gemm128<<<BG, 256, 0, stream>>>(hB, Wc[2], nullptr, t, N);
    k_aggregate<<<BA, 256, 0, stream>>>(t, offsets, srcs, norms, disq, bc[2], hA, N, 1);
    // Layer 3 (no relu): hA -> hB
    k_gemm128<<<BG, 256, 0, stream>>>(hA, Wc[3], nullptr, t, N);
    k_aggregate<<<BA, 256, 0, stream>>>(t, offsets, srcs, norms, disq, bc[3], hB, N, 0);
    // Output projection
    k_gemm128<<<BG, 256, 0, stream>>>(hB, Wout, bout, (float*)d_out, N);
}

// Round 2
// 1171.124 us; speedup vs baseline: 1.1766x; 1.1766x over previous
//
#include <hip/hip_runtime.h>

// ---------------------------------------------------------------------------
// GCN: 4x GCNConv(128->128) + final linear. fp32 end-to-end.
// CSR build per call (multi-block scan), then per layer: dense GEMM
// (t = h @ W) and CSR gather-aggregate. d_out doubles as GEMM scratch.
// ---------------------------------------------------------------------------

#define SCAN_CHUNK 1024   // counts per block in the 3-phase scan

__global__ __launch_bounds__(256) void k_init(float* deg, int* count, int n) {
    int i = blockIdx.x * 256 + threadIdx.x;
    if (i < n) { deg[i] = 1.0f; count[i] = 0; }   // self-loop weight 1
}

__global__ __launch_bounds__(256) void k_count(const int* __restrict__ col,
                                               const float* __restrict__ ew,
                                               float* deg, int* count, int E) {
    int e = blockIdx.x * 256 + threadIdx.x;
    if (e < E) {
        int c = col[e];
        atomicAdd(&deg[c], ew[e]);
        atomicAdd(&count[c], 1);
    }
}

__global__ __launch_bounds__(256) void k_disq(const float* __restrict__ deg,
                                              float* disq, int n) {
    int i = blockIdx.x * 256 + threadIdx.x;
    if (i < n) disq[i] = 1.0f / sqrtf(deg[i]);    // deg >= 1 always
}

// ---- 3-phase multi-block exclusive scan of count[0..n) -> offsets/cursor ----
// Phase 1: per-block sum of SCAN_CHUNK counts.
__global__ __launch_bounds__(256) void k_scan_part(const int* __restrict__ count,
                                                   int* __restrict__ partials, int n) {
    __shared__ int red[256];
    int t = threadIdx.x;
    int base = blockIdx.x * SCAN_CHUNK + t * 4;
    int s = 0;
#pragma unroll
    for (int j = 0; j < 4; j++) {
        int i = base + j;
        if (i < n) s += count[i];
    }
    red[t] = s;
    __syncthreads();
    for (int off = 128; off > 0; off >>= 1) {
        if (t < off) red[t] += red[t + off];
        __syncthreads();
    }
    if (t == 0) partials[blockIdx.x] = red[0];
}

// Phase 2: single small block scans the per-block partials (nb <= 1024).
__global__ __launch_bounds__(1024) void k_scan_top(const int* __restrict__ partials,
                                                   int* __restrict__ blockOff,
                                                   int* __restrict__ offsets,
                                                   int nb, int n) {
    __shared__ int sums[1024];
    int t = threadIdx.x;
    int v = (t < nb) ? partials[t] : 0;
    sums[t] = v;
    __syncthreads();
    for (int off = 1; off < 1024; off <<= 1) {
        int u = (t >= off) ? sums[t - off] : 0;
        __syncthreads();
        sums[t] += u;
        __syncthreads();
    }
    if (t < nb) blockOff[t] = sums[t] - v;       // exclusive
    if (t == nb - 1) offsets[n] = sums[t];       // grand total
}

// Phase 3: block-local exclusive scan + blockOff -> offsets & cursor.
__global__ __launch_bounds__(256) void k_scan_out(const int* __restrict__ count,
                                                  const int* __restrict__ blockOff,
                                                  int* __restrict__ offsets,
                                                  int* __restrict__ cursor, int n) {
    __shared__ int sums[256];
    int t = threadIdx.x;
    int base = blockIdx.x * SCAN_CHUNK + t * 4;
    int c[4]; int s = 0;
#pragma unroll
    for (int j = 0; j < 4; j++) {
        int i = base + j;
        c[j] = (i < n) ? count[i] : 0;
        s += c[j];
    }
    sums[t] = s;
    __syncthreads();
    for (int off = 1; off < 256; off <<= 1) {
        int u = (t >= off) ? sums[t - off] : 0;
        __syncthreads();
        sums[t] += u;
        __syncthreads();
    }
    int run = blockOff[blockIdx.x] + sums[t] - s;   // exclusive thread offset
#pragma unroll
    for (int j = 0; j < 4; j++) {
        int i = base + j;
        if (i < n) { offsets[i] = run; cursor[i] = run; }
        run += c[j];
    }
}

__global__ __launch_bounds__(256) void k_fill(const int* __restrict__ row,
                                              const int* __restrict__ col,
                                              const float* __restrict__ ew,
                                              const float* __restrict__ disq,
                                              int* cursor, int* __restrict__ srcs,
                                              float* __restrict__ norms, int E) {
    int e = blockIdx.x * 256 + threadIdx.x;
    if (e < E) {
        int c = col[e], r = row[e];
        int slot = atomicAdd(&cursor[c], 1);
        srcs[slot]  = r;
        norms[slot] = disq[r] * ew[e] * disq[c];
    }
}

// C = A @ W (+ bias). A: N x 128, W: 128 x 128 row-major. 128x128 block tile,
// 8x8 per-thread register tile, KB=32 LDS staging.
__global__ __launch_bounds__(256) void k_gemm128(const float* __restrict__ A,
                                                 const float* __restrict__ W,
                                                 const float* __restrict__ bias,
                                                 float* __restrict__ C, int N) {
    __shared__ float As[32][132];
    __shared__ float Ws[32][128];
    int tid = threadIdx.x;
    int tx = tid & 15, ty = tid >> 4;
    int rowBase = blockIdx.x * 128;

    float acc[8][8];
#pragma unroll
    for (int i = 0; i < 8; i++)
#pragma unroll
        for (int j = 0; j < 8; j++) acc[i][j] = 0.0f;

    for (int ks = 0; ks < 128; ks += 32) {
#pragma unroll
        for (int i = 0; i < 4; i++) {
            int lin = tid + i * 256;
            int r   = lin >> 3;
            int kq  = (lin & 7) << 2;
            int gr  = rowBase + r;
            float4 v = make_float4(0.f, 0.f, 0.f, 0.f);
            if (gr < N) v = *(const float4*)&A[(size_t)gr * 128 + ks + kq];
            As[kq + 0][r] = v.x;
            As[kq + 1][r] = v.y;
            As[kq + 2][r] = v.z;
            As[kq + 3][r] = v.w;
        }
#pragma unroll
        for (int i = 0; i < 4; i++) {
            int lin = tid + i * 256;
            int k   = lin >> 5;
            int cq  = (lin & 31) << 2;
            *(float4*)&Ws[k][cq] = *(const float4*)&W[(ks + k) * 128 + cq];
        }
        __syncthreads();
#pragma unroll
        for (int k = 0; k < 32; k++) {
            float4 a0 = *(const float4*)&As[k][ty * 8];
            float4 a1 = *(const float4*)&As[k][ty * 8 + 4];
            float4 b0 = *(const float4*)&Ws[k][tx * 8];
            float4 b1 = *(const float4*)&Ws[k][tx * 8 + 4];
            float a[8] = {a0.x, a0.y, a0.z, a0.w, a1.x, a1.y, a1.z, a1.w};
            float b[8] = {b0.x, b0.y, b0.z, b0.w, b1.x, b1.y, b1.z, b1.w};
#pragma unroll
            for (int i = 0; i < 8; i++)
#pragma unroll
                for (int j = 0; j < 8; j++) acc[i][j] += a[i] * b[j];
        }
        __syncthreads();
    }
#pragma unroll
    for (int i = 0; i < 8; i++) {
        int gr = rowBase + ty * 8 + i;
        if (gr < N) {
#pragma unroll
            for (int jq = 0; jq < 2; jq++) {
                int c0 = tx * 8 + jq * 4;
                float4 v;
                v.x = acc[i][jq * 4 + 0];
                v.y = acc[i][jq * 4 + 1];
                v.z = acc[i][jq * 4 + 2];
                v.w = acc[i][jq * 4 + 3];
                if (bias) {
                    v.x += bias[c0 + 0];
                    v.y += bias[c0 + 1];
                    v.z += bias[c0 + 2];
                    v.w += bias[c0 + 3];
                }
                *(float4*)&C[(size_t)gr * 128 + c0] = v;
            }
        }
    }
}

// One wave per node. Lane layout: half = lane>>5 (which edge of a pair),
// li = lane&31 (feature quad). Each iteration a half-wave loads one edge's
// 128-float row as float4 -> 2 edges per wave-wide load instruction.
// Final cross-half combine via shfl_xor(32); low half stores float4.
__global__ __launch_bounds__(256) void k_aggregate(const float* __restrict__ t,
                                                   const int* __restrict__ offsets,
                                                   const int* __restrict__ srcs,
                                                   const float* __restrict__ norms,
                                                   const float* __restrict__ disq,
                                                   const float* __restrict__ bias,
                                                   float* __restrict__ out,
                                                   int N, int relu) {
    int wave = threadIdx.x >> 6;
    int lane = threadIdx.x & 63;
    int node = blockIdx.x * 4 + wave;
    if (node >= N) return;
    int half = lane >> 5;
    int li   = lane & 31;

    float4 acc = make_float4(0.f, 0.f, 0.f, 0.f);
    float d = disq[node];
    if (half == 0) {   // self-loop + bias counted once
        float4 tv = *(const float4*)&t[(size_t)node * 128 + li * 4];
        float4 bv = *(const float4*)&bias[li * 4];
        float dd = d * d;
        acc.x = tv.x * dd + bv.x;
        acc.y = tv.y * dd + bv.y;
        acc.z = tv.z * dd + bv.z;
        acc.w = tv.w * dd + bv.w;
    }

    int e0 = offsets[node], e1 = offsets[node + 1];
    for (int eb = e0; eb < e1; eb += 64) {
        int n_e = min(64, e1 - eb);
        int   src_l  = 0;
        float norm_l = 0.f;
        if (lane < n_e) {
            src_l  = srcs[eb + lane];
            norm_l = norms[eb + lane];
        }
        int i = 0;
        // 4 edges per iteration: two half-wave pair loads, independent for ILP
        for (; i + 4 <= n_e; i += 4) {
            int   sA = __shfl(src_l,  i + half);
            float nA = __shfl(norm_l, i + half);
            int   sB = __shfl(src_l,  i + 2 + half);
            float nB = __shfl(norm_l, i + 2 + half);
            const float4 hA = *(const float4*)&t[(size_t)sA * 128 + li * 4];
            const float4 hB = *(const float4*)&t[(size_t)sB * 128 + li * 4];
            acc.x += nA * hA.x + nB * hB.x;
            acc.y += nA * hA.y + nB * hB.y;
            acc.z += nA * hA.z + nB * hB.z;
            acc.w += nA * hA.w + nB * hB.w;
        }
        for (; i + 2 <= n_e; i += 2) {
            int   sA = __shfl(src_l,  i + half);
            float nA = __shfl(norm_l, i + half);
            const float4 hA = *(const float4*)&t[(size_t)sA * 128 + li * 4];
            acc.x += nA * hA.x;
            acc.y += nA * hA.y;
            acc.z += nA * hA.z;
            acc.w += nA * hA.w;
        }
        if (i < n_e) {   // odd tail: shfl on all lanes, accumulate on half 0
            int   sA = __shfl(src_l,  i);
            float nA = __shfl(norm_l, i);
            if (half == 0) {
                const float4 hA = *(const float4*)&t[(size_t)sA * 128 + li * 4];
                acc.x += nA * hA.x;
                acc.y += nA * hA.y;
                acc.z += nA * hA.z;
                acc.w += nA * hA.w;
            }
        }
    }
    // combine halves
    acc.x += __shfl_xor(acc.x, 32);
    acc.y += __shfl_xor(acc.y, 32);
    acc.z += __shfl_xor(acc.z, 32);
    acc.w += __shfl_xor(acc.w, 32);
    if (half == 0) {
        if (relu) {
            acc.x = fmaxf(acc.x, 0.f);
            acc.y = fmaxf(acc.y, 0.f);
            acc.z = fmaxf(acc.z, 0.f);
            acc.w = fmaxf(acc.w, 0.f);
        }
        *(float4*)&out[(size_t)node * 128 + li * 4] = acc;
    }
}

extern "C" void kernel_launch(void* const* d_in, const int* in_sizes, int n_in,
                              void* d_out, int out_size, void* d_ws, size_t ws_size,
                              hipStream_t stream) {
    const float* x    = (const float*)d_in[0];
    const int*   ei   = (const int*)d_in[1];
    const float* ew   = (const float*)d_in[2];
    const float* Wc[4] = {(const float*)d_in[3], (const float*)d_in[5],
                          (const float*)d_in[7], (const float*)d_in[9]};
    const float* bc[4] = {(const float*)d_in[4], (const float*)d_in[6],
                          (const float*)d_in[8], (const float*)d_in[10]};
    const float* Wout = (const float*)d_in[11];
    const float* bout = (const float*)d_in[12];

    const int N = in_sizes[0] / 128;
    const int E = in_sizes[2];
    const int* row = ei;
    const int* col = ei + E;

    size_t off = 0;
    char* base = (char*)d_ws;
    auto alloc = [&](size_t bytes) -> void* {
        void* p = base + off;
        off += (bytes + 255) & ~(size_t)255;
        return p;
    };
    float* deg      = (float*)alloc((size_t)N * 4);
    float* disq     = (float*)alloc((size_t)N * 4);
    int*   count    = (int*)alloc((size_t)N * 4);
    int*   offsets  = (int*)alloc((size_t)(N + 1) * 4);
    int*   cursor   = (int*)alloc((size_t)N * 4);
    int*   partials = (int*)alloc(1024 * 4);
    int*   blockOff = (int*)alloc(1024 * 4);
    int*   srcs     = (int*)alloc((size_t)E * 4);
    float* norms    = (float*)alloc((size_t)E * 4);
    float* hA       = (float*)alloc((size_t)N * 128 * 4);
    float* hB       = (float*)alloc((size_t)N * 128 * 4);
    float* t        = (float*)d_out;

    const int BN = (N + 255) / 256;
    const int BE = (E + 255) / 256;
    const int BG = (N + 127) / 128;
    const int BA = (N + 3) / 4;
    const int NB = (N + SCAN_CHUNK - 1) / SCAN_CHUNK;   // scan blocks (<=1024)

    // CSR build
    k_init<<<BN, 256, 0, stream>>>(deg, count, N);
    k_count<<<BE, 256, 0, stream>>>(col, ew, deg, count, E);
    k_disq<<<BN, 256, 0, stream>>>(deg, disq, N);
    k_scan_part<<<NB, 256, 0, stream>>>(count, partials, N);
    k_scan_top<<<1, 1024, 0, stream>>>(partials, blockOff, offsets, NB, N);
    k_scan_out<<<NB, 256, 0, stream>>>(count, blockOff, offsets, cursor, N);
    k_fill<<<BE, 256, 0, stream>>>(row, col, ew, disq, cursor, srcs, norms, E);

    // Layer 0
    k_gemm128<<<BG, 256, 0, stream>>>(x, Wc[0], nullptr, t, N);
    k_aggregate<<<BA, 256, 0, stream>>>(t, offsets, srcs, norms, disq, bc[0], hA, N, 1);
    // Layer 1
    k_gemm128<<<BG, 256, 0, stream>>>(hA, Wc[1], nullptr, t, N);
    k_aggregate<<<BA, 256, 0, stream>>>(t, offsets, srcs, norms, disq, bc[1], hB, N, 1);
    // Layer 2
    k_gemm128<<<BG, 256, 0, stream>>>(hB, Wc[2], nullptr, t, N);
    k_aggregate<<<BA, 256, 0, stream>>>(t, offsets, srcs, norms, disq, bc[2], hA, N, 1);
    // Layer 3 (no relu)
    k_gemm128<<<BG, 256, 0, stream>>>(hA, Wc[3], nullptr, t, N);
    k_aggregate<<<BA, 256, 0, stream>>>(t, offsets, srcs, norms, disq, bc[3], hB, N, 0);
    // Output projection
    k_gemm128<<<BG, 256, 0, stream>>>(hB, Wout, bout, (float*)d_out, N);
}

// Round 3
// 852.665 us; speedup vs baseline: 1.6160x; 1.3735x over previous
//
#include <hip/hip_runtime.h>

// ---------------------------------------------------------------------------
// GCN: 4x GCNConv(128->128) + final linear.
// CSR build per call: count (1 atomic/edge) -> 3-phase scan -> fill (packed
// uint2{src,ew}, 1 atomic + 1 line/edge) -> segmented-sum deg -> norm scale.
// Per layer: GEMM h@W -> bf16 t (RTNE), then CSR gather-aggregate in fp32
// (disq[c] folded into the epilogue). Single in-place h buffer.
// ---------------------------------------------------------------------------

#define SCAN_CHUNK 1024

__device__ inline unsigned bf16pack(float a, float b) {  // RTNE pack of 2 floats
    unsigned ua = __float_as_uint(a);
    unsigned ub = __float_as_uint(b);
    ua = (ua + 0x7fffu + ((ua >> 16) & 1u)) >> 16;
    ub = (ub + 0x7fffu + ((ub >> 16) & 1u)) & 0xffff0000u;
    return ua | ub;
}

__device__ inline float4 bf16x4_expand(uint2 w) {
    float4 f;
    f.x = __uint_as_float(w.x << 16);
    f.y = __uint_as_float(w.x & 0xffff0000u);
    f.z = __uint_as_float(w.y << 16);
    f.w = __uint_as_float(w.y & 0xffff0000u);
    return f;
}

__global__ __launch_bounds__(256) void k_init(int* count, int n) {
    int i = blockIdx.x * 256 + threadIdx.x;
    if (i < n) count[i] = 0;
}

__global__ __launch_bounds__(256) void k_count(const int* __restrict__ col,
                                               int* count, int E) {
    int e = blockIdx.x * 256 + threadIdx.x;
    if (e < E) atomicAdd(&count[col[e]], 1);
}

// ---- 3-phase multi-block exclusive scan ----
__global__ __launch_bounds__(256) void k_scan_part(const int* __restrict__ count,
                                                   int* __restrict__ partials, int n) {
    __shared__ int red[256];
    int t = threadIdx.x;
    int base = blockIdx.x * SCAN_CHUNK + t * 4;
    int s = 0;
#pragma unroll
    for (int j = 0; j < 4; j++) {
        int i = base + j;
        if (i < n) s += count[i];
    }
    red[t] = s;
    __syncthreads();
    for (int off = 128; off > 0; off >>= 1) {
        if (t < off) red[t] += red[t + off];
        __syncthreads();
    }
    if (t == 0) partials[blockIdx.x] = red[0];
}

__global__ __launch_bounds__(1024) void k_scan_top(const int* __restrict__ partials,
                                                   int* __restrict__ blockOff,
                                                   int* __restrict__ offsets,
                                                   int nb, int n) {
    __shared__ int sums[1024];
    int t = threadIdx.x;
    int v = (t < nb) ? partials[t] : 0;
    sums[t] = v;
    __syncthreads();
    for (int off = 1; off < 1024; off <<= 1) {
        int u = (t >= off) ? sums[t - off] : 0;
        __syncthreads();
        sums[t] += u;
        __syncthreads();
    }
    if (t < nb) blockOff[t] = sums[t] - v;
    if (t == nb - 1) offsets[n] = sums[t];
}

// Writes offsets and cursor. cursor MAY alias count (read-before-write per idx).
__global__ __launch_bounds__(256) void k_scan_out(const int* __restrict__ count,
                                                  const int* __restrict__ blockOff,
                                                  int* __restrict__ offsets,
                                                  int* cursor, int n) {
    __shared__ int sums[256];
    int t = threadIdx.x;
    int base = blockIdx.x * SCAN_CHUNK + t * 4;
    int c[4]; int s = 0;
#pragma unroll
    for (int j = 0; j < 4; j++) {
        int i = base + j;
        c[j] = (i < n) ? count[i] : 0;
        s += c[j];
    }
    sums[t] = s;
    __syncthreads();
    for (int off = 1; off < 256; off <<= 1) {
        int u = (t >= off) ? sums[t - off] : 0;
        __syncthreads();
        sums[t] += u;
        __syncthreads();
    }
    int run = blockOff[blockIdx.x] + sums[t] - s;
#pragma unroll
    for (int j = 0; j < 4; j++) {
        int i = base + j;
        if (i < n) { offsets[i] = run; cursor[i] = run; }
        run += c[j];
    }
}

// Bin edges: one packed 8B store per edge (src, raw ew bits).
__global__ __launch_bounds__(256) void k_fill(const int* __restrict__ row,
                                              const int* __restrict__ col,
                                              const float* __restrict__ ew,
                                              int* cursor, uint2* __restrict__ edges,
                                              int E) {
    int e = blockIdx.x * 256 + threadIdx.x;
    if (e < E) {
        int c = col[e];
        int slot = atomicAdd(&cursor[c], 1);
        edges[slot] = make_uint2((unsigned)row[e], __float_as_uint(ew[e]));
    }
}

// Segmented sum of ew per node (contiguous CSR) -> disq = 1/sqrt(1+sum).
__global__ __launch_bounds__(256) void k_deg(const uint2* __restrict__ edges,
                                             const int* __restrict__ offsets,
                                             float* __restrict__ disq, int n) {
    int i = blockIdx.x * 256 + threadIdx.x;
    if (i >= n) return;
    int e0 = offsets[i], e1 = offsets[i + 1];
    float s = 1.0f;                       // self-loop weight
    for (int e = e0; e < e1; e++) s += __uint_as_float(edges[e].y);
    disq[i] = 1.0f / sqrtf(s);
}

// Scale stored ew by disq[src] (disq[dst] folded into aggregate epilogue).
__global__ __launch_bounds__(256) void k_norm(uint2* edges,
                                              const float* __restrict__ disq, int E) {
    int e = blockIdx.x * 256 + threadIdx.x;
    if (e < E) {
        uint2 m = edges[e];
        m.y = __float_as_uint(__uint_as_float(m.y) * disq[m.x]);
        edges[e] = m;
    }
}

// C = A @ W (+bias). A: N x 128 fp32, W: 128 x 128 fp32 row-major.
// BF16OUT: C is N x 128 bf16 (packed 64 words/row), else fp32.
template <bool BF16OUT>
__global__ __launch_bounds__(256) void k_gemm128(const float* __restrict__ A,
                                                 const float* __restrict__ W,
                                                 const float* __restrict__ bias,
                                                 void* __restrict__ Cout, int N) {
    __shared__ float As[32][132];
    __shared__ float Ws[32][128];
    int tid = threadIdx.x;
    int tx = tid & 15, ty = tid >> 4;
    int rowBase = blockIdx.x * 128;

    float acc[8][8];
#pragma unroll
    for (int i = 0; i < 8; i++)
#pragma unroll
        for (int j = 0; j < 8; j++) acc[i][j] = 0.0f;

    for (int ks = 0; ks < 128; ks += 32) {
#pragma unroll
        for (int i = 0; i < 4; i++) {
            int lin = tid + i * 256;
            int r   = lin >> 3;
            int kq  = (lin & 7) << 2;
            int gr  = rowBase + r;
            float4 v = make_float4(0.f, 0.f, 0.f, 0.f);
            if (gr < N) v = *(const float4*)&A[(size_t)gr * 128 + ks + kq];
            As[kq + 0][r] = v.x;
            As[kq + 1][r] = v.y;
            As[kq + 2][r] = v.z;
            As[kq + 3][r] = v.w;
        }
#pragma unroll
        for (int i = 0; i < 4; i++) {
            int lin = tid + i * 256;
            int k   = lin >> 5;
            int cq  = (lin & 31) << 2;
            *(float4*)&Ws[k][cq] = *(const float4*)&W[(ks + k) * 128 + cq];
        }
        __syncthreads();
#pragma unroll
        for (int k = 0; k < 32; k++) {
            float4 a0 = *(const float4*)&As[k][ty * 8];
            float4 a1 = *(const float4*)&As[k][ty * 8 + 4];
            float4 b0 = *(const float4*)&Ws[k][tx * 8];
            float4 b1 = *(const float4*)&Ws[k][tx * 8 + 4];
            float a[8] = {a0.x, a0.y, a0.z, a0.w, a1.x, a1.y, a1.z, a1.w};
            float b[8] = {b0.x, b0.y, b0.z, b0.w, b1.x, b1.y, b1.z, b1.w};
#pragma unroll
            for (int i = 0; i < 8; i++)
#pragma unroll
                for (int j = 0; j < 8; j++) acc[i][j] += a[i] * b[j];
        }
        __syncthreads();
    }
#pragma unroll
    for (int i = 0; i < 8; i++) {
        int gr = rowBase + ty * 8 + i;
        if (gr < N) {
            if (BF16OUT) {
                unsigned* Cb = (unsigned*)Cout;
                uint4 u;
                u.x = bf16pack(acc[i][0], acc[i][1]);
                u.y = bf16pack(acc[i][2], acc[i][3]);
                u.z = bf16pack(acc[i][4], acc[i][5]);
                u.w = bf16pack(acc[i][6], acc[i][7]);
                *(uint4*)&Cb[(size_t)gr * 64 + tx * 4] = u;
            } else {
                float* C = (float*)Cout;
#pragma unroll
                for (int jq = 0; jq < 2; jq++) {
                    int c0 = tx * 8 + jq * 4;
                    float4 v;
                    v.x = acc[i][jq * 4 + 0];
                    v.y = acc[i][jq * 4 + 1];
                    v.z = acc[i][jq * 4 + 2];
                    v.w = acc[i][jq * 4 + 3];
                    if (bias) {
                        v.x += bias[c0 + 0];
                        v.y += bias[c0 + 1];
                        v.z += bias[c0 + 2];
                        v.w += bias[c0 + 3];
                    }
                    *(float4*)&C[(size_t)gr * 128 + c0] = v;
                }
            }
        }
    }
}

// One wave per node. half = lane>>5 selects edge of a pair, li = lane&31 is
// the feature quad (4 bf16 = one uint2 = 8B per lane; 256B per edge row).
// out[c] = disq[c]*sum_e coef_e*t[src_e] + disq[c]^2*t[c] + bias ; opt. relu.
__global__ __launch_bounds__(256) void k_aggregate(const unsigned* __restrict__ tb,
                                                   const int* __restrict__ offsets,
                                                   const uint2* __restrict__ edges,
                                                   const float* __restrict__ disq,
                                                   const float* __restrict__ bias,
                                                   float* __restrict__ out,
                                                   int N, int relu) {
    int wave = threadIdx.x >> 6;
    int lane = threadIdx.x & 63;
    int node = blockIdx.x * 4 + wave;
    if (node >= N) return;
    int half = lane >> 5;
    int li   = lane & 31;

    float4 acc = make_float4(0.f, 0.f, 0.f, 0.f);

    int e0 = offsets[node], e1 = offsets[node + 1];
    for (int eb = e0; eb < e1; eb += 64) {
        int n_e = min(64, e1 - eb);
        int   src_l  = 0;
        float coef_l = 0.f;
        if (lane < n_e) {
            uint2 m = edges[eb + lane];
            src_l  = (int)m.x;
            coef_l = __uint_as_float(m.y);
        }
        int i = 0;
        // 8 edges / iter: 4 independent pair-loads in flight per half-wave.
        for (; i + 8 <= n_e; i += 8) {
            int   s0 = __shfl(src_l,  i + 0 + half);
            int   s1 = __shfl(src_l,  i + 2 + half);
            int   s2 = __shfl(src_l,  i + 4 + half);
            int   s3 = __shfl(src_l,  i + 6 + half);
            float n0 = __shfl(coef_l, i + 0 + half);
            float n1 = __shfl(coef_l, i + 2 + half);
            float n2 = __shfl(coef_l, i + 4 + half);
            float n3 = __shfl(coef_l, i + 6 + half);
            uint2 w0 = *(const uint2*)&tb[(size_t)s0 * 64 + li * 2];
            uint2 w1 = *(const uint2*)&tb[(size_t)s1 * 64 + li * 2];
            uint2 w2 = *(const uint2*)&tb[(size_t)s2 * 64 + li * 2];
            uint2 w3 = *(const uint2*)&tb[(size_t)s3 * 64 + li * 2];
            float4 f0 = bf16x4_expand(w0);
            float4 f1 = bf16x4_expand(w1);
            float4 f2 = bf16x4_expand(w2);
            float4 f3 = bf16x4_expand(w3);
            acc.x += n0 * f0.x + n1 * f1.x + n2 * f2.x + n3 * f3.x;
            acc.y += n0 * f0.y + n1 * f1.y + n2 * f2.y + n3 * f3.y;
            acc.z += n0 * f0.z + n1 * f1.z + n2 * f2.z + n3 * f3.z;
            acc.w += n0 * f0.w + n1 * f1.w + n2 * f2.w + n3 * f3.w;
        }
        for (; i + 2 <= n_e; i += 2) {
            int   s0 = __shfl(src_l,  i + half);
            float n0 = __shfl(coef_l, i + half);
            uint2 w0 = *(const uint2*)&tb[(size_t)s0 * 64 + li * 2];
            float4 f0 = bf16x4_expand(w0);
            acc.x += n0 * f0.x;
            acc.y += n0 * f0.y;
            acc.z += n0 * f0.z;
            acc.w += n0 * f0.w;
        }
        if (i < n_e) {        // odd tail, accumulate on half 0 only
            int   s0 = __shfl(src_l,  i);
            float n0 = __shfl(coef_l, i);
            if (half == 0) {
                uint2 w0 = *(const uint2*)&tb[(size_t)s0 * 64 + li * 2];
                float4 f0 = bf16x4_expand(w0);
                acc.x += n0 * f0.x;
                acc.y += n0 * f0.y;
                acc.z += n0 * f0.z;
                acc.w += n0 * f0.w;
            }
        }
    }
    acc.x += __shfl_xor(acc.x, 32);
    acc.y += __shfl_xor(acc.y, 32);
    acc.z += __shfl_xor(acc.z, 32);
    acc.w += __shfl_xor(acc.w, 32);
    if (half == 0) {
        float d  = disq[node];
        float dd = d * d;
        uint2 wv = *(const uint2*)&tb[(size_t)node * 64 + li * 2];
        float4 tv = bf16x4_expand(wv);
        float4 bv = *(const float4*)&bias[li * 4];
        float4 o;
        o.x = d * acc.x + dd * tv.x + bv.x;
        o.y = d * acc.y + dd * tv.y + bv.y;
        o.z = d * acc.z + dd * tv.z + bv.z;
        o.w = d * acc.w + dd * tv.w + bv.w;
        if (relu) {
            o.x = fmaxf(o.x, 0.f);
            o.y = fmaxf(o.y, 0.f);
            o.z = fmaxf(o.z, 0.f);
            o.w = fmaxf(o.w, 0.f);
        }
        *(float4*)&out[(size_t)node * 128 + li * 4] = o;
    }
}

extern "C" void kernel_launch(void* const* d_in, const int* in_sizes, int n_in,
                              void* d_out, int out_size, void* d_ws, size_t ws_size,
                              hipStream_t stream) {
    const float* x    = (const float*)d_in[0];
    const int*   ei   = (const int*)d_in[1];
    const float* ew   = (const float*)d_in[2];
    const float* Wc[4] = {(const float*)d_in[3], (const float*)d_in[5],
                          (const float*)d_in[7], (const float*)d_in[9]};
    const float* bc[4] = {(const float*)d_in[4], (const float*)d_in[6],
                          (const float*)d_in[8], (const float*)d_in[10]};
    const float* Wout = (const float*)d_in[11];
    const float* bout = (const float*)d_in[12];

    const int N = in_sizes[0] / 128;
    const int E = in_sizes[2];
    const int* row = ei;
    const int* col = ei + E;

    size_t off = 0;
    char* base = (char*)d_ws;
    auto alloc = [&](size_t bytes) -> void* {
        void* p = base + off;
        off += (bytes + 255) & ~(size_t)255;
        return p;
    };
    float*    disq     = (float*)alloc((size_t)N * 4);
    int*      count    = (int*)alloc((size_t)N * 4);       // aliased as cursor
    int*      offsets  = (int*)alloc((size_t)(N + 1) * 4);
    int*      partials = (int*)alloc(1024 * 4);
    int*      blockOff = (int*)alloc(1024 * 4);
    uint2*    edges    = (uint2*)alloc((size_t)E * 8);
    float*    h        = (float*)alloc((size_t)N * 128 * 4);
    unsigned* tb       = (unsigned*)alloc((size_t)N * 64 * 4);   // bf16 t

    const int BN = (N + 255) / 256;
    const int BE = (E + 255) / 256;
    const int BG = (N + 127) / 128;
    const int BA = (N + 3) / 4;
    const int NB = (N + SCAN_CHUNK - 1) / SCAN_CHUNK;

    // CSR build
    k_init<<<BN, 256, 0, stream>>>(count, N);
    k_count<<<BE, 256, 0, stream>>>(col, count, E);
    k_scan_part<<<NB, 256, 0, stream>>>(count, partials, N);
    k_scan_top<<<1, 1024, 0, stream>>>(partials, blockOff, offsets, NB, N);
    k_scan_out<<<NB, 256, 0, stream>>>(count, blockOff, offsets, count, N);
    k_fill<<<BE, 256, 0, stream>>>(row, col, ew, count, edges, E);
    k_deg<<<BN, 256, 0, stream>>>(edges, offsets, disq, N);
    k_norm<<<BE, 256, 0, stream>>>(edges, disq, E);

    // Layer 0 (reads x), layers 1-3 in-place on h
    k_gemm128<true><<<BG, 256, 0, stream>>>(x, Wc[0], nullptr, tb, N);
    k_aggregate<<<BA, 256, 0, stream>>>(tb, offsets, edges, disq, bc[0], h, N, 1);
    k_gemm128<true><<<BG, 256, 0, stream>>>(h, Wc[1], nullptr, tb, N);
    k_aggregate<<<BA, 256, 0, stream>>>(tb, offsets, edges, disq, bc[1], h, N, 1);
    k_gemm128<true><<<BG, 256, 0, stream>>>(h, Wc[2], nullptr, tb, N);
    k_aggregate<<<BA, 256, 0, stream>>>(tb, offsets, edges, disq, bc[2], h, N, 1);
    k_gemm128<true><<<BG, 256, 0, stream>>>(h, Wc[3], nullptr, tb, N);
    k_aggregate<<<BA, 256, 0, stream>>>(tb, offsets, edges, disq, bc[3], h, N, 0);
    // Output projection (fp32 out with bias)
    k_gemm128<false><<<BG, 256, 0, stream>>>(h, Wout, bout, d_out, N);
}

// Round 4
// 744.458 us; speedup vs baseline: 1.8509x; 1.1454x over previous
//
#include <hip/hip_runtime.h>

// ---------------------------------------------------------------------------
// GCN: 4x GCNConv(128->128) + final linear.
// CSR build with ZERO global atomics: two-level counting sort.
//   L1: per-block LDS histogram over K=ceil(N/256) buckets -> [K][B1] hist
//       -> 3-phase scan -> LDS-cursor scatter (bucket-grouped, L2-merged).
//   L2: one block per bucket: in-LDS counting sort by node; emits final
//       node-sorted edges, per-node offsets, and disq (=rsqrt(1+sum ew)).
// Per layer: GEMM t' = disq*(h@W) -> bf16, then gather-aggregate
//   out[c] = disq[c]*(sum_e ew_e * t'[src_e] + t'[c]) + bias (opt. relu).
// Aggregate: quarter-wave gather (16 lanes x 16B = full 256B bf16 row),
// 16 edges in flight per wave.
// ---------------------------------------------------------------------------

#define SCAN_CHUNK 1024
#define NBUCK_MAX  512     // LDS histogram capacity (K = 391 for N = 100000)
#define BCAP       6144    // per-bucket edge capacity (avg 4092, sigma ~64)

__device__ inline unsigned bf16pack(float a, float b) {  // RTNE pack
    unsigned ua = __float_as_uint(a);
    unsigned ub = __float_as_uint(b);
    ua = (ua + 0x7fffu + ((ua >> 16) & 1u)) >> 16;
    ub = (ub + 0x7fffu + ((ub >> 16) & 1u)) & 0xffff0000u;
    return ua | ub;
}

__device__ inline void bf16x8_expand(uint4 w, float4& a, float4& b) {
    a.x = __uint_as_float(w.x << 16);
    a.y = __uint_as_float(w.x & 0xffff0000u);
    a.z = __uint_as_float(w.y << 16);
    a.w = __uint_as_float(w.y & 0xffff0000u);
    b.x = __uint_as_float(w.z << 16);
    b.y = __uint_as_float(w.z & 0xffff0000u);
    b.z = __uint_as_float(w.w << 16);
    b.w = __uint_as_float(w.w & 0xffff0000u);
}

// ---- Level-1 pass A: per-block bucket histogram. hist laid out [K][B1]. ----
__global__ __launch_bounds__(256) void k_hist(const int* __restrict__ col,
                                              int* __restrict__ hist,
                                              int E, int K, int B1, int chunk) {
    __shared__ int cnt[NBUCK_MAX];
    int b = blockIdx.x, t = threadIdx.x;
    for (int k = t; k < K; k += 256) cnt[k] = 0;
    __syncthreads();
    int e0 = b * chunk, e1 = min(e0 + chunk, E);
    for (int e = e0 + t; e < e1; e += 256) atomicAdd(&cnt[col[e] >> 8], 1);
    __syncthreads();
    for (int k = t; k < K; k += 256) hist[k * B1 + b] = cnt[k];
}

// ---- 3-phase multi-block exclusive scan (generic over n) ----
__global__ __launch_bounds__(256) void k_scan_part(const int* __restrict__ count,
                                                   int* __restrict__ partials, int n) {
    __shared__ int red[256];
    int t = threadIdx.x;
    int base = blockIdx.x * SCAN_CHUNK + t * 4;
    int s = 0;
#pragma unroll
    for (int j = 0; j < 4; j++) {
        int i = base + j;
        if (i < n) s += count[i];
    }
    red[t] = s;
    __syncthreads();
    for (int off = 128; off > 0; off >>= 1) {
        if (t < off) red[t] += red[t + off];
        __syncthreads();
    }
    if (t == 0) partials[blockIdx.x] = red[0];
}

__global__ __launch_bounds__(1024) void k_scan_top(const int* __restrict__ partials,
                                                   int* __restrict__ blockOff,
                                                   int* __restrict__ result,
                                                   int nb, int n) {
    __shared__ int sums[1024];
    int t = threadIdx.x;
    int v = (t < nb) ? partials[t] : 0;
    sums[t] = v;
    __syncthreads();
    for (int off = 1; off < 1024; off <<= 1) {
        int u = (t >= off) ? sums[t - off] : 0;
        __syncthreads();
        sums[t] += u;
        __syncthreads();
    }
    if (t < nb) blockOff[t] = sums[t] - v;
    if (t == nb - 1) result[n] = sums[t];   // grand total sentinel
}

__global__ __launch_bounds__(256) void k_scan_out(const int* __restrict__ count,
                                                  const int* __restrict__ blockOff,
                                                  int* __restrict__ result, int n) {
    __shared__ int sums[256];
    int t = threadIdx.x;
    int base = blockIdx.x * SCAN_CHUNK + t * 4;
    int c[4]; int s = 0;
#pragma unroll
    for (int j = 0; j < 4; j++) {
        int i = base + j;
        c[j] = (i < n) ? count[i] : 0;
        s += c[j];
    }
    sums[t] = s;
    __syncthreads();
    for (int off = 1; off < 256; off <<= 1) {
        int u = (t >= off) ? sums[t - off] : 0;
        __syncthreads();
        sums[t] += u;
        __syncthreads();
    }
    int run = blockOff[blockIdx.x] + sums[t] - s;
#pragma unroll
    for (int j = 0; j < 4; j++) {
        int i = base + j;
        if (i < n) result[i] = run;
        run += c[j];
    }
}

// ---- Level-1 pass B: scatter edges into bucket-grouped order. ----
// word0 = src | (col_local << 24)  (src < 2^24, col_local < 256)
__global__ __launch_bounds__(256) void k_scatter(const int* __restrict__ row,
                                                 const int* __restrict__ col,
                                                 const float* __restrict__ ew,
                                                 const int* __restrict__ binBase,
                                                 uint2* __restrict__ etmp,
                                                 int E, int K, int B1, int chunk) {
    __shared__ int cur[NBUCK_MAX];
    int b = blockIdx.x, t = threadIdx.x;
    for (int k = t; k < K; k += 256) cur[k] = binBase[k * B1 + b];
    __syncthreads();
    int e0 = b * chunk, e1 = min(e0 + chunk, E);
    for (int e = e0 + t; e < e1; e += 256) {
        int c = col[e];
        int k = c >> 8;
        int pos = atomicAdd(&cur[k], 1);
        etmp[pos] = make_uint2((unsigned)row[e] | ((unsigned)(c & 255) << 24),
                               __float_as_uint(ew[e]));
    }
}

// ---- Level-2: per-bucket in-LDS counting sort by node; emit offsets/disq. ----
__global__ __launch_bounds__(256) void k_bucket(const uint2* __restrict__ etmp,
                                                const int* __restrict__ binBase,
                                                uint2* __restrict__ edges,
                                                int* __restrict__ offsets,
                                                float* __restrict__ disq,
                                                int N, int K, int B1) {
    __shared__ unsigned ls[BCAP];   // src | col_local<<24
    __shared__ unsigned lw[BCAP];   // ew bits
    __shared__ int   cnt[256];
    __shared__ float sew[256];
    __shared__ int   excl[257];
    int k = blockIdx.x, t = threadIdx.x;
    int bStart = binBase[k * B1];
    int bEnd   = binBase[(k + 1) * B1];   // sentinel at K*B1 = E
    int size   = bEnd - bStart;
    cnt[t] = 0; sew[t] = 0.f;
    __syncthreads();
    for (int i = t; i < size && i < BCAP; i += 256) {
        uint2 m = etmp[bStart + i];
        ls[i] = m.x; lw[i] = m.y;
        int j = m.x >> 24;
        atomicAdd(&cnt[j], 1);
        atomicAdd(&sew[j], __uint_as_float(m.y));
    }
    __syncthreads();
    // Hillis-Steele inclusive scan into excl[t+1]; excl[0]=0.
    excl[t + 1] = cnt[t];
    if (t == 0) excl[0] = 0;
    __syncthreads();
    for (int off = 1; off < 256; off <<= 1) {
        int add = (t + 1 > off) ? excl[t + 1 - off] : 0;
        __syncthreads();
        excl[t + 1] += add;
        __syncthreads();
    }
    int node = (k << 8) + t;
    if (node < N) {
        offsets[node] = bStart + excl[t];
        disq[node]    = rsqrtf(1.0f + sew[t]);
    }
    if (k == K - 1 && t == 0) offsets[N] = bEnd;
    cnt[t] = excl[t];        // cursors
    __syncthreads();
    for (int i = t; i < size && i < BCAP; i += 256) {
        unsigned s = ls[i];
        int j = s >> 24;
        int pos = atomicAdd(&cnt[j], 1);
        edges[bStart + pos] = make_uint2(s & 0x00FFFFFFu, lw[i]);
    }
}

// C = A @ W. BF16OUT: write disq[row]*(A@W) as packed bf16 (t'); else fp32+bias.
template <bool BF16OUT>
__global__ __launch_bounds__(256) void k_gemm128(const float* __restrict__ A,
                                                 const float* __restrict__ W,
                                                 const float* __restrict__ bias,
                                                 const float* __restrict__ disq,
                                                 void* __restrict__ Cout, int N) {
    __shared__ float As[32][132];
    __shared__ float Ws[32][128];
    int tid = threadIdx.x;
    int tx = tid & 15, ty = tid >> 4;
    int rowBase = blockIdx.x * 128;

    float acc[8][8];
#pragma unroll
    for (int i = 0; i < 8; i++)
#pragma unroll
        for (int j = 0; j < 8; j++) acc[i][j] = 0.0f;

    for (int ks = 0; ks < 128; ks += 32) {
#pragma unroll
        for (int i = 0; i < 4; i++) {
            int lin = tid + i * 256;
            int r   = lin >> 3;
            int kq  = (lin & 7) << 2;
            int gr  = rowBase + r;
            float4 v = make_float4(0.f, 0.f, 0.f, 0.f);
            if (gr < N) v = *(const float4*)&A[(size_t)gr * 128 + ks + kq];
            As[kq + 0][r] = v.x;
            As[kq + 1][r] = v.y;
            As[kq + 2][r] = v.z;
            As[kq + 3][r] = v.w;
        }
#pragma unroll
        for (int i = 0; i < 4; i++) {
            int lin = tid + i * 256;
            int k   = lin >> 5;
            int cq  = (lin & 31) << 2;
            *(float4*)&Ws[k][cq] = *(const float4*)&W[(ks + k) * 128 + cq];
        }
        __syncthreads();
#pragma unroll
        for (int k = 0; k < 32; k++) {
            float4 a0 = *(const float4*)&As[k][ty * 8];
            float4 a1 = *(const float4*)&As[k][ty * 8 + 4];
            float4 b0 = *(const float4*)&Ws[k][tx * 8];
            float4 b1 = *(const float4*)&Ws[k][tx * 8 + 4];
            float a[8] = {a0.x, a0.y, a0.z, a0.w, a1.x, a1.y, a1.z, a1.w};
            float b[8] = {b0.x, b0.y, b0.z, b0.w, b1.x, b1.y, b1.z, b1.w};
#pragma unroll
            for (int i = 0; i < 8; i++)
#pragma unroll
                for (int j = 0; j < 8; j++) acc[i][j] += a[i] * b[j];
        }
        __syncthreads();
    }
#pragma unroll
    for (int i = 0; i < 8; i++) {
        int gr = rowBase + ty * 8 + i;
        if (gr < N) {
            if (BF16OUT) {
                float d = disq[gr];
                unsigned* Cb = (unsigned*)Cout;
                uint4 u;
                u.x = bf16pack(acc[i][0] * d, acc[i][1] * d);
                u.y = bf16pack(acc[i][2] * d, acc[i][3] * d);
                u.z = bf16pack(acc[i][4] * d, acc[i][5] * d);
                u.w = bf16pack(acc[i][6] * d, acc[i][7] * d);
                *(uint4*)&Cb[(size_t)gr * 64 + tx * 4] = u;
            } else {
                float* C = (float*)Cout;
#pragma unroll
                for (int jq = 0; jq < 2; jq++) {
                    int c0 = tx * 8 + jq * 4;
                    float4 v;
                    v.x = acc[i][jq * 4 + 0] + bias[c0 + 0];
                    v.y = acc[i][jq * 4 + 1] + bias[c0 + 1];
                    v.z = acc[i][jq * 4 + 2] + bias[c0 + 2];
                    v.w = acc[i][jq * 4 + 3] + bias[c0 + 3];
                    *(float4*)&C[(size_t)gr * 128 + c0] = v;
                }
            }
        }
    }
}

// One wave per node; quarter q = lane>>4 owns one edge per load group,
// li = lane&15 covers 16B (8 bf16) of the 256B row. 16 edges in flight/wave.
// Lanes >= n_e carry coef 0 / src 0, so no tail special-casing is needed.
__global__ __launch_bounds__(256) void k_aggregate(const unsigned* __restrict__ tb,
                                                   const int* __restrict__ offsets,
                                                   const uint2* __restrict__ edges,
                                                   const float* __restrict__ disq,
                                                   const float* __restrict__ bias,
                                                   float* __restrict__ out,
                                                   int N, int relu) {
    int wave = threadIdx.x >> 6;
    int lane = threadIdx.x & 63;
    int node = blockIdx.x * 4 + wave;
    if (node >= N) return;
    int q  = lane >> 4;
    int li = lane & 15;

    float4 acc0 = make_float4(0.f, 0.f, 0.f, 0.f);
    float4 acc1 = make_float4(0.f, 0.f, 0.f, 0.f);

    int e0 = offsets[node], e1 = offsets[node + 1];
    for (int eb = e0; eb < e1; eb += 64) {
        int n_e = min(64, e1 - eb);
        int src_l = 0; float coef_l = 0.f;
        if (lane < n_e) {
            uint2 m = edges[eb + lane];
            src_l  = (int)m.x;
            coef_l = __uint_as_float(m.y);
        }
        int i = 0;
        for (; i + 16 <= n_e; i += 16) {
            int   s0 = __shfl(src_l,  i + q);
            int   s1 = __shfl(src_l,  i + 4 + q);
            int   s2 = __shfl(src_l,  i + 8 + q);
            int   s3 = __shfl(src_l,  i + 12 + q);
            float n0 = __shfl(coef_l, i + q);
            float n1 = __shfl(coef_l, i + 4 + q);
            float n2 = __shfl(coef_l, i + 8 + q);
            float n3 = __shfl(coef_l, i + 12 + q);
            uint4 w0 = *(const uint4*)&tb[(size_t)s0 * 64 + li * 4];
            uint4 w1 = *(const uint4*)&tb[(size_t)s1 * 64 + li * 4];
            uint4 w2 = *(const uint4*)&tb[(size_t)s2 * 64 + li * 4];
            uint4 w3 = *(const uint4*)&tb[(size_t)s3 * 64 + li * 4];
            float4 a, b;
            bf16x8_expand(w0, a, b);
            acc0.x += n0 * a.x; acc0.y += n0 * a.y; acc0.z += n0 * a.z; acc0.w += n0 * a.w;
            acc1.x += n0 * b.x; acc1.y += n0 * b.y; acc1.z += n0 * b.z; acc1.w += n0 * b.w;
            bf16x8_expand(w1, a, b);
            acc0.x += n1 * a.x; acc0.y += n1 * a.y; acc0.z += n1 * a.z; acc0.w += n1 * a.w;
            acc1.x += n1 * b.x; acc1.y += n1 * b.y; acc1.z += n1 * b.z; acc1.w += n1 * b.w;
            bf16x8_expand(w2, a, b);
            acc0.x += n2 * a.x; acc0.y += n2 * a.y; acc0.z += n2 * a.z; acc0.w += n2 * a.w;
            acc1.x += n2 * b.x; acc1.y += n2 * b.y; acc1.z += n2 * b.z; acc1.w += n2 * b.w;
            bf16x8_expand(w3, a, b);
            acc0.x += n3 * a.x; acc0.y += n3 * a.y; acc0.z += n3 * a.z; acc0.w += n3 * a.w;
            acc1.x += n3 * b.x; acc1.y += n3 * b.y; acc1.z += n3 * b.z; acc1.w += n3 * b.w;
        }
        for (; i < n_e; i += 4) {
            int idx = i + q; if (idx > 63) idx = 63;   // clamped lanes carry coef 0
            int   s0 = __shfl(src_l,  idx);
            float n0 = __shfl(coef_l, idx);
            uint4 w0 = *(const uint4*)&tb[(size_t)s0 * 64 + li * 4];
            float4 a, b;
            bf16x8_expand(w0, a, b);
            acc0.x += n0 * a.x; acc0.y += n0 * a.y; acc0.z += n0 * a.z; acc0.w += n0 * a.w;
            acc1.x += n0 * b.x; acc1.y += n0 * b.y; acc1.z += n0 * b.z; acc1.w += n0 * b.w;
        }
    }
#pragma unroll
    for (int m = 16; m <= 32; m <<= 1) {
        acc0.x += __shfl_xor(acc0.x, m);
        acc0.y += __shfl_xor(acc0.y, m);
        acc0.z += __shfl_xor(acc0.z, m);
        acc0.w += __shfl_xor(acc0.w, m);
        acc1.x += __shfl_xor(acc1.x, m);
        acc1.y += __shfl_xor(acc1.y, m);
        acc1.z += __shfl_xor(acc1.z, m);
        acc1.w += __shfl_xor(acc1.w, m);
    }
    if (q == 0) {
        float d = disq[node];
        uint4 wv = *(const uint4*)&tb[(size_t)node * 64 + li * 4];
        float4 ta, tbv;
        bf16x8_expand(wv, ta, tbv);
        float4 b0 = *(const float4*)&bias[li * 8];
        float4 b1 = *(const float4*)&bias[li * 8 + 4];
        float4 o0, o1;
        o0.x = d * (acc0.x + ta.x) + b0.x;
        o0.y = d * (acc0.y + ta.y) + b0.y;
        o0.z = d * (acc0.z + ta.z) + b0.z;
        o0.w = d * (acc0.w + ta.w) + b0.w;
        o1.x = d * (acc1.x + tbv.x) + b1.x;
        o1.y = d * (acc1.y + tbv.y) + b1.y;
        o1.z = d * (acc1.z + tbv.z) + b1.z;
        o1.w = d * (acc1.w + tbv.w) + b1.w;
        if (relu) {
            o0.x = fmaxf(o0.x, 0.f); o0.y = fmaxf(o0.y, 0.f);
            o0.z = fmaxf(o0.z, 0.f); o0.w = fmaxf(o0.w, 0.f);
            o1.x = fmaxf(o1.x, 0.f); o1.y = fmaxf(o1.y, 0.f);
            o1.z = fmaxf(o1.z, 0.f); o1.w = fmaxf(o1.w, 0.f);
        }
        *(float4*)&out[(size_t)node * 128 + li * 8]     = o0;
        *(float4*)&out[(size_t)node * 128 + li * 8 + 4] = o1;
    }
}

extern "C" void kernel_launch(void* const* d_in, const int* in_sizes, int n_in,
                              void* d_out, int out_size, void* d_ws, size_t ws_size,
                              hipStream_t stream) {
    const float* x    = (const float*)d_in[0];
    const int*   ei   = (const int*)d_in[1];
    const float* ew   = (const float*)d_in[2];
    const float* Wc[4] = {(const float*)d_in[3], (const float*)d_in[5],
                          (const float*)d_in[7], (const float*)d_in[9]};
    const float* bc[4] = {(const float*)d_in[4], (const float*)d_in[6],
                          (const float*)d_in[8], (const float*)d_in[10]};
    const float* Wout = (const float*)d_in[11];
    const float* bout = (const float*)d_in[12];

    const int N = in_sizes[0] / 128;
    const int E = in_sizes[2];
    const int* row = ei;
    const int* col = ei + E;

    const int K     = (N + 255) >> 8;            // buckets (391)
    const int B1    = 256;                        // level-1 blocks
    const int chunk = (E + B1 - 1) / B1;
    const int nScan = K * B1;

    size_t off = 0;
    char* base = (char*)d_ws;
    auto alloc = [&](size_t bytes) -> void* {
        void* p = base + off;
        off += (bytes + 255) & ~(size_t)255;
        return p;
    };
    float*    disq     = (float*)alloc((size_t)N * 4);
    int*      offsets  = (int*)alloc((size_t)(N + 1) * 4);
    int*      hist     = (int*)alloc((size_t)nScan * 4);
    int*      binBase  = (int*)alloc((size_t)(nScan + 1) * 4);
    int*      partials = (int*)alloc(1024 * 4);
    int*      blockOff = (int*)alloc(1024 * 4);
    uint2*    etmp     = (uint2*)alloc((size_t)E * 8);
    uint2*    edges    = (uint2*)alloc((size_t)E * 8);
    float*    h        = (float*)alloc((size_t)N * 128 * 4);
    unsigned* tb       = (unsigned*)alloc((size_t)N * 64 * 4);

    const int BG  = (N + 127) / 128;
    const int BA  = (N + 3) / 4;
    const int NBs = (nScan + SCAN_CHUNK - 1) / SCAN_CHUNK;

    // CSR build (no global atomics)
    k_hist<<<B1, 256, 0, stream>>>(col, hist, E, K, B1, chunk);
    k_scan_part<<<NBs, 256, 0, stream>>>(hist, partials, nScan);
    k_scan_top<<<1, 1024, 0, stream>>>(partials, blockOff, binBase, NBs, nScan);
    k_scan_out<<<NBs, 256, 0, stream>>>(hist, blockOff, binBase, nScan);
    k_scatter<<<B1, 256, 0, stream>>>(row, col, ew, binBase, etmp, E, K, B1, chunk);
    k_bucket<<<K, 256, 0, stream>>>(etmp, binBase, edges, offsets, disq, N, K, B1);

    // Layers
    k_gemm128<true><<<BG, 256, 0, stream>>>(x, Wc[0], nullptr, disq, tb, N);
    k_aggregate<<<BA, 256, 0, stream>>>(tb, offsets, edges, disq, bc[0], h, N, 1);
    k_gemm128<true><<<BG, 256, 0, stream>>>(h, Wc[1], nullptr, disq, tb, N);
    k_aggregate<<<BA, 256, 0, stream>>>(tb, offsets, edges, disq, bc[1], h, N, 1);
    k_gemm128<true><<<BG, 256, 0, stream>>>(h, Wc[2], nullptr, disq, tb, N);
    k_aggregate<<<BA, 256, 0, stream>>>(tb, offsets, edges, disq, bc[2], h, N, 1);
    k_gemm128<true><<<BG, 256, 0, stream>>>(h, Wc[3], nullptr, disq, tb, N);
    k_aggregate<<<BA, 256, 0, stream>>>(tb, offsets, edges, disq, bc[3], h, N, 0);
    // Output projection (fp32 + bias)
    k_gemm128<false><<<BG, 256, 0, stream>>>(h, Wout, bout, nullptr, d_out, N);
}

// Round 5
// 584.778 us; speedup vs baseline: 2.3563x; 1.2731x over previous
//
#include <hip/hip_runtime.h>

// ---------------------------------------------------------------------------
// GCN: 4x GCNConv(128->128) + final linear.
// CSR build with zero global atomics (two-level counting sort), then per
// layer: split-bf16 MFMA GEMM t' = disq*(h@W) (fp32-grade via hi/lo split),
// CSR gather-aggregate out[c] = disq[c]*(sum ew*t'[src] + t'[c]) + b.
// GEMM computes D = W^T · h^T so the MFMA C/D fragment gives 4 consecutive
// features per lane -> packed 8B bf16 stores (no transpose epilogue).
// ---------------------------------------------------------------------------

#define SCAN_CHUNK 1024
#define NBUCK_MAX  512
#define BCAP       6144

typedef __attribute__((ext_vector_type(8))) short bf16x8;
typedef __attribute__((ext_vector_type(4))) float f32x4;

__device__ inline unsigned bf16pack(float a, float b) {  // RTNE pack, a->low
    unsigned ua = __float_as_uint(a);
    unsigned ub = __float_as_uint(b);
    ua = (ua + 0x7fffu + ((ua >> 16) & 1u)) >> 16;
    ub = (ub + 0x7fffu + ((ub >> 16) & 1u)) & 0xffff0000u;
    return ua | ub;
}

__device__ inline void split2(float x, ushort& hi, ushort& lo) {
    unsigned u = __float_as_uint(x);
    unsigned r = (u + 0x7fffu + ((u >> 16) & 1u)) & 0xffff0000u;
    hi = (ushort)(r >> 16);
    float rem = x - __uint_as_float(r);
    unsigned u2 = __float_as_uint(rem);
    lo = (ushort)((u2 + 0x7fffu + ((u2 >> 16) & 1u)) >> 16);
}

__device__ inline void bf16x8_expand(uint4 w, float4& a, float4& b) {
    a.x = __uint_as_float(w.x << 16);
    a.y = __uint_as_float(w.x & 0xffff0000u);
    a.z = __uint_as_float(w.y << 16);
    a.w = __uint_as_float(w.y & 0xffff0000u);
    b.x = __uint_as_float(w.z << 16);
    b.y = __uint_as_float(w.z & 0xffff0000u);
    b.z = __uint_as_float(w.w << 16);
    b.w = __uint_as_float(w.w & 0xffff0000u);
}

// ---- W prep: transpose + hi/lo bf16 split of 5 weight matrices ----
// Out layout: WT[n][k] (k contiguous), 128x128 each, widx-major.
__global__ __launch_bounds__(256) void k_prepw(const float* W0, const float* W1,
                                               const float* W2, const float* W3,
                                               const float* W4,
                                               ushort* __restrict__ hiO,
                                               ushort* __restrict__ loO) {
    const float* W = (blockIdx.x == 0) ? W0 : (blockIdx.x == 1) ? W1 :
                     (blockIdx.x == 2) ? W2 : (blockIdx.x == 3) ? W3 : W4;
    ushort* h = hiO + (size_t)blockIdx.x * 16384;
    ushort* l = loO + (size_t)blockIdx.x * 16384;
    for (int idx = threadIdx.x; idx < 4096; idx += 256) {
        int n  = idx >> 5;
        int kq = (idx & 31) * 4;
        ushort hs[4], ls[4];
#pragma unroll
        for (int j = 0; j < 4; j++) split2(W[(kq + j) * 128 + n], hs[j], ls[j]);
        *(uint2*)&h[n * 128 + kq] =
            make_uint2(hs[0] | ((unsigned)hs[1] << 16), hs[2] | ((unsigned)hs[3] << 16));
        *(uint2*)&l[n * 128 + kq] =
            make_uint2(ls[0] | ((unsigned)ls[1] << 16), ls[2] | ((unsigned)ls[3] << 16));
    }
}

// ---- Level-1 pass A: per-block bucket histogram. hist laid out [K][B1]. ----
__global__ __launch_bounds__(256) void k_hist(const int* __restrict__ col,
                                              int* __restrict__ hist,
                                              int E, int K, int B1, int chunk) {
    __shared__ int cnt[NBUCK_MAX];
    int b = blockIdx.x, t = threadIdx.x;
    for (int k = t; k < K; k += 256) cnt[k] = 0;
    __syncthreads();
    int e0 = b * chunk, e1 = min(e0 + chunk, E);
    for (int e = e0 + t; e < e1; e += 256) atomicAdd(&cnt[col[e] >> 8], 1);
    __syncthreads();
    for (int k = t; k < K; k += 256) hist[k * B1 + b] = cnt[k];
}

// ---- 3-phase multi-block exclusive scan ----
__global__ __launch_bounds__(256) void k_scan_part(const int* __restrict__ count,
                                                   int* __restrict__ partials, int n) {
    __shared__ int red[256];
    int t = threadIdx.x;
    int base = blockIdx.x * SCAN_CHUNK + t * 4;
    int s = 0;
#pragma unroll
    for (int j = 0; j < 4; j++) {
        int i = base + j;
        if (i < n) s += count[i];
    }
    red[t] = s;
    __syncthreads();
    for (int off = 128; off > 0; off >>= 1) {
        if (t < off) red[t] += red[t + off];
        __syncthreads();
    }
    if (t == 0) partials[blockIdx.x] = red[0];
}

__global__ __launch_bounds__(1024) void k_scan_top(const int* __restrict__ partials,
                                                   int* __restrict__ blockOff,
                                                   int* __restrict__ result,
                                                   int nb, int n) {
    __shared__ int sums[1024];
    int t = threadIdx.x;
    int v = (t < nb) ? partials[t] : 0;
    sums[t] = v;
    __syncthreads();
    for (int off = 1; off < 1024; off <<= 1) {
        int u = (t >= off) ? sums[t - off] : 0;
        __syncthreads();
        sums[t] += u;
        __syncthreads();
    }
    if (t < nb) blockOff[t] = sums[t] - v;
    if (t == nb - 1) result[n] = sums[t];
}

__global__ __launch_bounds__(256) void k_scan_out(const int* __restrict__ count,
                                                  const int* __restrict__ blockOff,
                                                  int* __restrict__ result, int n) {
    __shared__ int sums[256];
    int t = threadIdx.x;
    int base = blockIdx.x * SCAN_CHUNK + t * 4;
    int c[4]; int s = 0;
#pragma unroll
    for (int j = 0; j < 4; j++) {
        int i = base + j;
        c[j] = (i < n) ? count[i] : 0;
        s += c[j];
    }
    sums[t] = s;
    __syncthreads();
    for (int off = 1; off < 256; off <<= 1) {
        int u = (t >= off) ? sums[t - off] : 0;
        __syncthreads();
        sums[t] += u;
        __syncthreads();
    }
    int run = blockOff[blockIdx.x] + sums[t] - s;
#pragma unroll
    for (int j = 0; j < 4; j++) {
        int i = base + j;
        if (i < n) result[i] = run;
        run += c[j];
    }
}

// ---- Level-1 pass B: scatter edges into bucket-grouped order. ----
__global__ __launch_bounds__(256) void k_scatter(const int* __restrict__ row,
                                                 const int* __restrict__ col,
                                                 const float* __restrict__ ew,
                                                 const int* __restrict__ binBase,
                                                 uint2* __restrict__ etmp,
                                                 int E, int K, int B1, int chunk) {
    __shared__ int cur[NBUCK_MAX];
    int b = blockIdx.x, t = threadIdx.x;
    for (int k = t; k < K; k += 256) cur[k] = binBase[k * B1 + b];
    __syncthreads();
    int e0 = b * chunk, e1 = min(e0 + chunk, E);
    for (int e = e0 + t; e < e1; e += 256) {
        int c = col[e];
        int k = c >> 8;
        int pos = atomicAdd(&cur[k], 1);
        etmp[pos] = make_uint2((unsigned)row[e] | ((unsigned)(c & 255) << 24),
                               __float_as_uint(ew[e]));
    }
}

// ---- Level-2: per-bucket in-LDS counting sort; emit edges/offsets/disq. ----
__global__ __launch_bounds__(256) void k_bucket(const uint2* __restrict__ etmp,
                                                const int* __restrict__ binBase,
                                                uint2* __restrict__ edges,
                                                int* __restrict__ offsets,
                                                float* __restrict__ disq,
                                                int N, int K, int B1) {
    __shared__ unsigned ls[BCAP];
    __shared__ unsigned lw[BCAP];
    __shared__ int   cnt[256];
    __shared__ float sew[256];
    __shared__ int   excl[257];
    int k = blockIdx.x, t = threadIdx.x;
    int bStart = binBase[k * B1];
    int bEnd   = binBase[(k + 1) * B1];
    int size   = bEnd - bStart;
    cnt[t] = 0; sew[t] = 0.f;
    __syncthreads();
    for (int i = t; i < size && i < BCAP; i += 256) {
        uint2 m = etmp[bStart + i];
        ls[i] = m.x; lw[i] = m.y;
        int j = m.x >> 24;
        atomicAdd(&cnt[j], 1);
        atomicAdd(&sew[j], __uint_as_float(m.y));
    }
    __syncthreads();
    excl[t + 1] = cnt[t];
    if (t == 0) excl[0] = 0;
    __syncthreads();
    for (int off = 1; off < 256; off <<= 1) {
        int add = (t + 1 > off) ? excl[t + 1 - off] : 0;
        __syncthreads();
        excl[t + 1] += add;
        __syncthreads();
    }
    int node = (k << 8) + t;
    if (node < N) {
        offsets[node] = bStart + excl[t];
        disq[node]    = rsqrtf(1.0f + sew[t]);
    }
    if (k == K - 1 && t == 0) offsets[N] = bEnd;
    cnt[t] = excl[t];
    __syncthreads();
    for (int i = t; i < size && i < BCAP; i += 256) {
        unsigned s = ls[i];
        int j = s >> 24;
        int pos = atomicAdd(&cnt[j], 1);
        edges[bStart + pos] = make_uint2(s & 0x00FFFFFFu, lw[i]);
    }
}

// ---- Split-bf16 MFMA GEMM: D = W^T * h^T (fp32-grade). ----
// Block: 128 nodes x 128 features; wave: 32 nodes x 128 features.
// A-operand = WT frag (m=feature), B-operand = h row frag (n=node).
// C/D: col(lane&15)=node, row(quad*4+reg)=feature -> 4 consecutive features
// per lane -> packed stores. BF16OUT: t' = disq*acc as bf16; else fp32+bias.
template <bool BF16OUT>
__global__ __launch_bounds__(256) void k_gemm_mfma(const float* __restrict__ A,
                                                   const ushort* __restrict__ WThi,
                                                   const ushort* __restrict__ WTlo,
                                                   const float* __restrict__ bias,
                                                   const float* __restrict__ disq,
                                                   void* __restrict__ Cout, int N) {
    __shared__ ushort Whi_s[128][136];   // [n][k], 136-pad: 16B-aligned rows, 2-way banks
    __shared__ ushort Wlo_s[128][136];
    int tid = threadIdx.x;
#pragma unroll
    for (int r = 0; r < 8; r++) {
        int n  = r * 16 + (tid >> 4);
        int kq = (tid & 15) * 8;
        *(uint4*)&Whi_s[n][kq] = *(const uint4*)&WThi[n * 128 + kq];
        *(uint4*)&Wlo_s[n][kq] = *(const uint4*)&WTlo[n * 128 + kq];
    }
    __syncthreads();

    int wv = tid >> 6, ln = tid & 63;
    int quad = ln >> 4, col = ln & 15;
    int nodeBase = blockIdx.x * 128 + wv * 32;
    int node0 = nodeBase + col, node1 = nodeBase + 16 + col;

    f32x4 acc[2][8];
#pragma unroll
    for (int nb = 0; nb < 2; nb++)
#pragma unroll
        for (int f = 0; f < 8; f++) acc[nb][f] = (f32x4)0.f;

    for (int s = 0; s < 4; s++) {
        int k0 = s * 32 + quad * 8;
        float v0[8], v1[8];
#pragma unroll
        for (int j = 0; j < 8; j++) { v0[j] = 0.f; v1[j] = 0.f; }
        if (node0 < N) {
            float4 a = *(const float4*)&A[(size_t)node0 * 128 + k0];
            float4 b = *(const float4*)&A[(size_t)node0 * 128 + k0 + 4];
            v0[0] = a.x; v0[1] = a.y; v0[2] = a.z; v0[3] = a.w;
            v0[4] = b.x; v0[5] = b.y; v0[6] = b.z; v0[7] = b.w;
        }
        if (node1 < N) {
            float4 a = *(const float4*)&A[(size_t)node1 * 128 + k0];
            float4 b = *(const float4*)&A[(size_t)node1 * 128 + k0 + 4];
            v1[0] = a.x; v1[1] = a.y; v1[2] = a.z; v1[3] = a.w;
            v1[4] = b.x; v1[5] = b.y; v1[6] = b.z; v1[7] = b.w;
        }
        bf16x8 bh0, bl0, bh1, bl1;
#pragma unroll
        for (int j = 0; j < 8; j++) {
            ushort h, l;
            split2(v0[j], h, l); bh0[j] = (short)h; bl0[j] = (short)l;
            split2(v1[j], h, l); bh1[j] = (short)h; bl1[j] = (short)l;
        }
#pragma unroll
        for (int f = 0; f < 8; f++) {
            bf16x8 wh = *(const bf16x8*)&Whi_s[f * 16 + col][k0];
            bf16x8 wl = *(const bf16x8*)&Wlo_s[f * 16 + col][k0];
            acc[0][f] = __builtin_amdgcn_mfma_f32_16x16x32_bf16(wh, bh0, acc[0][f], 0, 0, 0);
            acc[1][f] = __builtin_amdgcn_mfma_f32_16x16x32_bf16(wh, bh1, acc[1][f], 0, 0, 0);
            acc[0][f] = __builtin_amdgcn_mfma_f32_16x16x32_bf16(wl, bh0, acc[0][f], 0, 0, 0);
            acc[1][f] = __builtin_amdgcn_mfma_f32_16x16x32_bf16(wl, bh1, acc[1][f], 0, 0, 0);
            acc[0][f] = __builtin_amdgcn_mfma_f32_16x16x32_bf16(wh, bl0, acc[0][f], 0, 0, 0);
            acc[1][f] = __builtin_amdgcn_mfma_f32_16x16x32_bf16(wh, bl1, acc[1][f], 0, 0, 0);
        }
    }
#pragma unroll
    for (int nb = 0; nb < 2; nb++) {
        int node = nodeBase + nb * 16 + col;
        if (node >= N) continue;
        if (BF16OUT) {
            float d = disq[node];
            unsigned* tb = (unsigned*)Cout;
#pragma unroll
            for (int f = 0; f < 8; f++) {
                f32x4 a = acc[nb][f];
                uint2 u;
                u.x = bf16pack(a[0] * d, a[1] * d);
                u.y = bf16pack(a[2] * d, a[3] * d);
                *(uint2*)&tb[(size_t)node * 64 + f * 8 + quad * 2] = u;
            }
        } else {
            float* C = (float*)Cout;
#pragma unroll
            for (int f = 0; f < 8; f++) {
                int fb = f * 16 + quad * 4;
                float4 bv = *(const float4*)&bias[fb];
                f32x4 a = acc[nb][f];
                float4 o;
                o.x = a[0] + bv.x; o.y = a[1] + bv.y;
                o.z = a[2] + bv.z; o.w = a[3] + bv.w;
                *(float4*)&C[(size_t)node * 128 + fb] = o;
            }
        }
    }
}

// ---- Gather-aggregate: one wave per node, quarter-wave per edge row. ----
__global__ __launch_bounds__(256) void k_aggregate(const unsigned* __restrict__ tb,
                                                   const int* __restrict__ offsets,
                                                   const uint2* __restrict__ edges,
                                                   const float* __restrict__ disq,
                                                   const float* __restrict__ bias,
                                                   float* __restrict__ out,
                                                   int N, int relu) {
    int wave = threadIdx.x >> 6;
    int lane = threadIdx.x & 63;
    int node = blockIdx.x * 4 + wave;
    if (node >= N) return;
    int q  = lane >> 4;
    int li = lane & 15;

    float4 acc0 = make_float4(0.f, 0.f, 0.f, 0.f);
    float4 acc1 = make_float4(0.f, 0.f, 0.f, 0.f);

    int e0 = offsets[node], e1 = offsets[node + 1];
    for (int eb = e0; eb < e1; eb += 64) {
        int n_e = min(64, e1 - eb);
        int src_l = 0; float coef_l = 0.f;
        if (lane < n_e) {
            uint2 m = edges[eb + lane];
            src_l  = (int)m.x;
            coef_l = __uint_as_float(m.y);
        }
        int i = 0;
        for (; i + 16 <= n_e; i += 16) {
            int   s0 = __shfl(src_l,  i + q);
            int   s1 = __shfl(src_l,  i + 4 + q);
            int   s2 = __shfl(src_l,  i + 8 + q);
            int   s3 = __shfl(src_l,  i + 12 + q);
            float n0 = __shfl(coef_l, i + q);
            float n1 = __shfl(coef_l, i + 4 + q);
            float n2 = __shfl(coef_l, i + 8 + q);
            float n3 = __shfl(coef_l, i + 12 + q);
            uint4 w0 = *(const uint4*)&tb[(size_t)s0 * 64 + li * 4];
            uint4 w1 = *(const uint4*)&tb[(size_t)s1 * 64 + li * 4];
            uint4 w2 = *(const uint4*)&tb[(size_t)s2 * 64 + li * 4];
            uint4 w3 = *(const uint4*)&tb[(size_t)s3 * 64 + li * 4];
            float4 a, b;
            bf16x8_expand(w0, a, b);
            acc0.x += n0 * a.x; acc0.y += n0 * a.y; acc0.z += n0 * a.z; acc0.w += n0 * a.w;
            acc1.x += n0 * b.x; acc1.y += n0 * b.y; acc1.z += n0 * b.z; acc1.w += n0 * b.w;
            bf16x8_expand(w1, a, b);
            acc0.x += n1 * a.x; acc0.y += n1 * a.y; acc0.z += n1 * a.z; acc0.w += n1 * a.w;
            acc1.x += n1 * b.x; acc1.y += n1 * b.y; acc1.z += n1 * b.z; acc1.w += n1 * b.w;
            bf16x8_expand(w2, a, b);
            acc0.x += n2 * a.x; acc0.y += n2 * a.y; acc0.z += n2 * a.z; acc0.w += n2 * a.w;
            acc1.x += n2 * b.x; acc1.y += n2 * b.y; acc1.z += n2 * b.z; acc1.w += n2 * b.w;
            bf16x8_expand(w3, a, b);
            acc0.x += n3 * a.x; acc0.y += n3 * a.y; acc0.z += n3 * a.z; acc0.w += n3 * a.w;
            acc1.x += n3 * b.x; acc1.y += n3 * b.y; acc1.z += n3 * b.z; acc1.w += n3 * b.w;
        }
        for (; i < n_e; i += 4) {
            int idx = i + q; if (idx > 63) idx = 63;
            int   s0 = __shfl(src_l,  idx);
            float n0 = __shfl(coef_l, idx);
            uint4 w0 = *(const uint4*)&tb[(size_t)s0 * 64 + li * 4];
            float4 a, b;
            bf16x8_expand(w0, a, b);
            acc0.x += n0 * a.x; acc0.y += n0 * a.y; acc0.z += n0 * a.z; acc0.w += n0 * a.w;
            acc1.x += n0 * b.x; acc1.y += n0 * b.y; acc1.z += n0 * b.z; acc1.w += n0 * b.w;
        }
    }
#pragma unroll
    for (int m = 16; m <= 32; m <<= 1) {
        acc0.x += __shfl_xor(acc0.x, m);
        acc0.y += __shfl_xor(acc0.y, m);
        acc0.z += __shfl_xor(acc0.z, m);
        acc0.w += __shfl_xor(acc0.w, m);
        acc1.x += __shfl_xor(acc1.x, m);
        acc1.y += __shfl_xor(acc1.y, m);
        acc1.z += __shfl_xor(acc1.z, m);
        acc1.w += __shfl_xor(acc1.w, m);
    }
    if (q == 0) {
        float d = disq[node];
        uint4 wv = *(const uint4*)&tb[(size_t)node * 64 + li * 4];
        float4 ta, tbv;
        bf16x8_expand(wv, ta, tbv);
        float4 b0 = *(const float4*)&bias[li * 8];
        float4 b1 = *(const float4*)&bias[li * 8 + 4];
        float4 o0, o1;
        o0.x = d * (acc0.x + ta.x) + b0.x;
        o0.y = d * (acc0.y + ta.y) + b0.y;
        o0.z = d * (acc0.z + ta.z) + b0.z;
        o0.w = d * (acc0.w + ta.w) + b0.w;
        o1.x = d * (acc1.x + tbv.x) + b1.x;
        o1.y = d * (acc1.y + tbv.y) + b1.y;
        o1.z = d * (acc1.z + tbv.z) + b1.z;
        o1.w = d * (acc1.w + tbv.w) + b1.w;
        if (relu) {
            o0.x = fmaxf(o0.x, 0.f); o0.y = fmaxf(o0.y, 0.f);
            o0.z = fmaxf(o0.z, 0.f); o0.w = fmaxf(o0.w, 0.f);
            o1.x = fmaxf(o1.x, 0.f); o1.y = fmaxf(o1.y, 0.f);
            o1.z = fmaxf(o1.z, 0.f); o1.w = fmaxf(o1.w, 0.f);
        }
        *(float4*)&out[(size_t)node * 128 + li * 8]     = o0;
        *(float4*)&out[(size_t)node * 128 + li * 8 + 4] = o1;
    }
}

extern "C" void kernel_launch(void* const* d_in, const int* in_sizes, int n_in,
                              void* d_out, int out_size, void* d_ws, size_t ws_size,
                              hipStream_t stream) {
    const float* x    = (const float*)d_in[0];
    const int*   ei   = (const int*)d_in[1];
    const float* ew   = (const float*)d_in[2];
    const float* Wc[4] = {(const float*)d_in[3], (const float*)d_in[5],
                          (const float*)d_in[7], (const float*)d_in[9]};
    const float* bc[4] = {(const float*)d_in[4], (const float*)d_in[6],
                          (const float*)d_in[8], (const float*)d_in[10]};
    const float* Wout = (const float*)d_in[11];
    const float* bout = (const float*)d_in[12];

    const int N = in_sizes[0] / 128;
    const int E = in_sizes[2];
    const int* row = ei;
    const int* col = ei + E;

    const int K     = (N + 255) >> 8;
    const int B1    = 256;
    const int chunk = (E + B1 - 1) / B1;
    const int nScan = K * B1;

    size_t off = 0;
    char* base = (char*)d_ws;
    auto alloc = [&](size_t bytes) -> void* {
        void* p = base + off;
        off += (bytes + 255) & ~(size_t)255;
        return p;
    };
    float*    disq     = (float*)alloc((size_t)N * 4);
    int*      offsets  = (int*)alloc((size_t)(N + 1) * 4);
    int*      hist     = (int*)alloc((size_t)nScan * 4);
    int*      binBase  = (int*)alloc((size_t)(nScan + 1) * 4);
    int*      partials = (int*)alloc(1024 * 4);
    int*      blockOff = (int*)alloc(1024 * 4);
    ushort*   WThi     = (ushort*)alloc((size_t)5 * 16384 * 2);
    ushort*   WTlo     = (ushort*)alloc((size_t)5 * 16384 * 2);
    uint2*    etmp     = (uint2*)alloc((size_t)E * 8);
    uint2*    edges    = (uint2*)alloc((size_t)E * 8);
    float*    h        = (float*)alloc((size_t)N * 128 * 4);
    unsigned* tb       = (unsigned*)alloc((size_t)N * 64 * 4);

    const int BG  = (N + 127) / 128;
    const int BA  = (N + 3) / 4;
    const int NBs = (nScan + SCAN_CHUNK - 1) / SCAN_CHUNK;

    // Weight prep + CSR build (no global atomics)
    k_prepw<<<5, 256, 0, stream>>>(Wc[0], Wc[1], Wc[2], Wc[3], Wout, WThi, WTlo);
    k_hist<<<B1, 256, 0, stream>>>(col, hist, E, K, B1, chunk);
    k_scan_part<<<NBs, 256, 0, stream>>>(hist, partials, nScan);
    k_scan_top<<<1, 1024, 0, stream>>>(partials, blockOff, binBase, NBs, nScan);
    k_scan_out<<<NBs, 256, 0, stream>>>(hist, blockOff, binBase, nScan);
    k_scatter<<<B1, 256, 0, stream>>>(row, col, ew, binBase, etmp, E, K, B1, chunk);
    k_bucket<<<K, 256, 0, stream>>>(etmp, binBase, edges, offsets, disq, N, K, B1);

    // Layers (GEMM -> aggregate), single in-place h buffer
    k_gemm_mfma<true><<<BG, 256, 0, stream>>>(x, WThi, WTlo, nullptr, disq, tb, N);
    k_aggregate<<<BA, 256, 0, stream>>>(tb, offsets, edges, disq, bc[0], h, N, 1);
    k_gemm_mfma<true><<<BG, 256, 0, stream>>>(h, WThi + 16384, WTlo + 16384, nullptr, disq, tb, N);
    k_aggregate<<<BA, 256, 0, stream>>>(tb, offsets, edges, disq, bc[1], h, N, 1);
    k_gemm_mfma<true><<<BG, 256, 0, stream>>>(h, WThi + 32768, WTlo + 32768, nullptr, disq, tb, N);
    k_aggregate<<<BA, 256, 0, stream>>>(tb, offsets, edges, disq, bc[2], h, N, 1);
    k_gemm_mfma<true><<<BG, 256, 0, stream>>>(h, WThi + 49152, WTlo + 49152, nullptr, disq, tb, N);
    k_aggregate<<<BA, 256, 0, stream>>>(tb, offsets, edges, disq, bc[3], h, N, 0);
    // Output projection (fp32 + bias)
    k_gemm_mfma<false><<<BG, 256, 0, stream>>>(h, WThi + 65536, WTlo + 65536, bout, nullptr, d_out, N);
}

// Round 6
// 581.414 us; speedup vs baseline: 2.3699x; 1.0058x over previous
//
#include <hip/hip_runtime.h>

// ---------------------------------------------------------------------------
// GCN: 4x GCNConv(128->128) + final linear.
// CSR build with zero global atomics (two-level counting sort).
// Per layer: MFMA GEMM t' = disq*(h@W) (W split hi/lo bf16 -> fp32-grade;
// h is bf16 from layer 1 on), then CSR gather-aggregate
//   out[c] = disq[c]*(sum ew*t'[src] + t'[c]) + bias  (bf16 packed output).
// Aggregate: quarter-wave per edge row, direct same-line meta broadcast
// (no shfl), rotating 4-slot software pipeline to overlap gather latency.
// ---------------------------------------------------------------------------

#define SCAN_CHUNK 1024
#define NBUCK_MAX  512
#define BCAP       6144

typedef __attribute__((ext_vector_type(8))) short bf16x8;
typedef __attribute__((ext_vector_type(4))) float f32x4;

__device__ inline unsigned bf16pack(float a, float b) {  // RTNE pack, a->low
    unsigned ua = __float_as_uint(a);
    unsigned ub = __float_as_uint(b);
    ua = (ua + 0x7fffu + ((ua >> 16) & 1u)) >> 16;
    ub = (ub + 0x7fffu + ((ub >> 16) & 1u)) & 0xffff0000u;
    return ua | ub;
}

__device__ inline void split2(float x, ushort& hi, ushort& lo) {
    unsigned u = __float_as_uint(x);
    unsigned r = (u + 0x7fffu + ((u >> 16) & 1u)) & 0xffff0000u;
    hi = (ushort)(r >> 16);
    float rem = x - __uint_as_float(r);
    unsigned u2 = __float_as_uint(rem);
    lo = (ushort)((u2 + 0x7fffu + ((u2 >> 16) & 1u)) >> 16);
}

__device__ inline void bf16x8_expand(uint4 w, float4& a, float4& b) {
    a.x = __uint_as_float(w.x << 16);
    a.y = __uint_as_float(w.x & 0xffff0000u);
    a.z = __uint_as_float(w.y << 16);
    a.w = __uint_as_float(w.y & 0xffff0000u);
    b.x = __uint_as_float(w.z << 16);
    b.y = __uint_as_float(w.z & 0xffff0000u);
    b.z = __uint_as_float(w.w << 16);
    b.w = __uint_as_float(w.w & 0xffff0000u);
}

// ---- W prep: transpose + hi/lo bf16 split of 5 weight matrices ----
__global__ __launch_bounds__(256) void k_prepw(const float* W0, const float* W1,
                                               const float* W2, const float* W3,
                                               const float* W4,
                                               ushort* __restrict__ hiO,
                                               ushort* __restrict__ loO) {
    const float* W = (blockIdx.x == 0) ? W0 : (blockIdx.x == 1) ? W1 :
                     (blockIdx.x == 2) ? W2 : (blockIdx.x == 3) ? W3 : W4;
    ushort* h = hiO + (size_t)blockIdx.x * 16384;
    ushort* l = loO + (size_t)blockIdx.x * 16384;
    for (int idx = threadIdx.x; idx < 4096; idx += 256) {
        int n  = idx >> 5;
        int kq = (idx & 31) * 4;
        ushort hs[4], ls[4];
#pragma unroll
        for (int j = 0; j < 4; j++) split2(W[(kq + j) * 128 + n], hs[j], ls[j]);
        *(uint2*)&h[n * 128 + kq] =
            make_uint2(hs[0] | ((unsigned)hs[1] << 16), hs[2] | ((unsigned)hs[3] << 16));
        *(uint2*)&l[n * 128 + kq] =
            make_uint2(ls[0] | ((unsigned)ls[1] << 16), ls[2] | ((unsigned)ls[3] << 16));
    }
}

// ---- Level-1 pass A: per-block bucket histogram. hist laid out [K][B1]. ----
__global__ __launch_bounds__(256) void k_hist(const int* __restrict__ col,
                                              int* __restrict__ hist,
                                              int E, int K, int B1, int chunk) {
    __shared__ int cnt[NBUCK_MAX];
    int b = blockIdx.x, t = threadIdx.x;
    for (int k = t; k < K; k += 256) cnt[k] = 0;
    __syncthreads();
    int e0 = b * chunk, e1 = min(e0 + chunk, E);
    for (int e = e0 + t; e < e1; e += 256) atomicAdd(&cnt[col[e] >> 8], 1);
    __syncthreads();
    for (int k = t; k < K; k += 256) hist[k * B1 + b] = cnt[k];
}

// ---- 3-phase multi-block exclusive scan ----
__global__ __launch_bounds__(256) void k_scan_part(const int* __restrict__ count,
                                                   int* __restrict__ partials, int n) {
    __shared__ int red[256];
    int t = threadIdx.x;
    int base = blockIdx.x * SCAN_CHUNK + t * 4;
    int s = 0;
#pragma unroll
    for (int j = 0; j < 4; j++) {
        int i = base + j;
        if (i < n) s += count[i];
    }
    red[t] = s;
    __syncthreads();
    for (int off = 128; off > 0; off >>= 1) {
        if (t < off) red[t] += red[t + off];
        __syncthreads();
    }
    if (t == 0) partials[blockIdx.x] = red[0];
}

__global__ __launch_bounds__(1024) void k_scan_top(const int* __restrict__ partials,
                                                   int* __restrict__ blockOff,
                                                   int* __restrict__ result,
                                                   int nb, int n) {
    __shared__ int sums[1024];
    int t = threadIdx.x;
    int v = (t < nb) ? partials[t] : 0;
    sums[t] = v;
    __syncthreads();
    for (int off = 1; off < 1024; off <<= 1) {
        int u = (t >= off) ? sums[t - off] : 0;
        __syncthreads();
        sums[t] += u;
        __syncthreads();
    }
    if (t < nb) blockOff[t] = sums[t] - v;
    if (t == nb - 1) result[n] = sums[t];
}

__global__ __launch_bounds__(256) void k_scan_out(const int* __restrict__ count,
                                                  const int* __restrict__ blockOff,
                                                  int* __restrict__ result, int n) {
    __shared__ int sums[256];
    int t = threadIdx.x;
    int base = blockIdx.x * SCAN_CHUNK + t * 4;
    int c[4]; int s = 0;
#pragma unroll
    for (int j = 0; j < 4; j++) {
        int i = base + j;
        c[j] = (i < n) ? count[i] : 0;
        s += c[j];
    }
    sums[t] = s;
    __syncthreads();
    for (int off = 1; off < 256; off <<= 1) {
        int u = (t >= off) ? sums[t - off] : 0;
        __syncthreads();
        sums[t] += u;
        __syncthreads();
    }
    int run = blockOff[blockIdx.x] + sums[t] - s;
#pragma unroll
    for (int j = 0; j < 4; j++) {
        int i = base + j;
        if (i < n) result[i] = run;
        run += c[j];
    }
}

// ---- Level-1 pass B: scatter edges into bucket-grouped order. ----
__global__ __launch_bounds__(256) void k_scatter(const int* __restrict__ row,
                                                 const int* __restrict__ col,
                                                 const float* __restrict__ ew,
                                                 const int* __restrict__ binBase,
                                                 uint2* __restrict__ etmp,
                                                 int E, int K, int B1, int chunk) {
    __shared__ int cur[NBUCK_MAX];
    int b = blockIdx.x, t = threadIdx.x;
    for (int k = t; k < K; k += 256) cur[k] = binBase[k * B1 + b];
    __syncthreads();
    int e0 = b * chunk, e1 = min(e0 + chunk, E);
    for (int e = e0 + t; e < e1; e += 256) {
        int c = col[e];
        int k = c >> 8;
        int pos = atomicAdd(&cur[k], 1);
        etmp[pos] = make_uint2((unsigned)row[e] | ((unsigned)(c & 255) << 24),
                               __float_as_uint(ew[e]));
    }
}

// ---- Level-2: per-bucket in-LDS counting sort; emit edges/offsets/disq. ----
__global__ __launch_bounds__(256) void k_bucket(const uint2* __restrict__ etmp,
                                                const int* __restrict__ binBase,
                                                uint2* __restrict__ edges,
                                                int* __restrict__ offsets,
                                                float* __restrict__ disq,
                                                int N, int K, int B1) {
    __shared__ unsigned ls[BCAP];
    __shared__ unsigned lw[BCAP];
    __shared__ int   cnt[256];
    __shared__ float sew[256];
    __shared__ int   excl[257];
    int k = blockIdx.x, t = threadIdx.x;
    int bStart = binBase[k * B1];
    int bEnd   = binBase[(k + 1) * B1];
    int size   = bEnd - bStart;
    cnt[t] = 0; sew[t] = 0.f;
    __syncthreads();
    for (int i = t; i < size && i < BCAP; i += 256) {
        uint2 m = etmp[bStart + i];
        ls[i] = m.x; lw[i] = m.y;
        int j = m.x >> 24;
        atomicAdd(&cnt[j], 1);
        atomicAdd(&sew[j], __uint_as_float(m.y));
    }
    __syncthreads();
    excl[t + 1] = cnt[t];
    if (t == 0) excl[0] = 0;
    __syncthreads();
    for (int off = 1; off < 256; off <<= 1) {
        int add = (t + 1 > off) ? excl[t + 1 - off] : 0;
        __syncthreads();
        excl[t + 1] += add;
        __syncthreads();
    }
    int node = (k << 8) + t;
    if (node < N) {
        offsets[node] = bStart + excl[t];
        disq[node]    = rsqrtf(1.0f + sew[t]);
    }
    if (k == K - 1 && t == 0) offsets[N] = bEnd;
    cnt[t] = excl[t];
    __syncthreads();
    for (int i = t; i < size && i < BCAP; i += 256) {
        unsigned s = ls[i];
        int j = s >> 24;
        int pos = atomicAdd(&cnt[j], 1);
        edges[bStart + pos] = make_uint2(s & 0x00FFFFFFu, lw[i]);
    }
}

// ---- MFMA GEMM, fp32 A (layer 0 only): split A hi/lo, 3 MFMAs/frag. ----
// D = W^T * h^T; C/D col=node, row=feature quad -> packed bf16 stores.
__global__ __launch_bounds__(256) void k_gemm_f32A(const float* __restrict__ A,
                                                   const ushort* __restrict__ WThi,
                                                   const ushort* __restrict__ WTlo,
                                                   const float* __restrict__ disq,
                                                   unsigned* __restrict__ Cout, int N) {
    __shared__ ushort Whi_s[128][136];
    __shared__ ushort Wlo_s[128][136];
    int tid = threadIdx.x;
#pragma unroll
    for (int r = 0; r < 8; r++) {
        int n  = r * 16 + (tid >> 4);
        int kq = (tid & 15) * 8;
        *(uint4*)&Whi_s[n][kq] = *(const uint4*)&WThi[n * 128 + kq];
        *(uint4*)&Wlo_s[n][kq] = *(const uint4*)&WTlo[n * 128 + kq];
    }
    __syncthreads();

    int wv = tid >> 6, ln = tid & 63;
    int quad = ln >> 4, col = ln & 15;
    int nodeBase = blockIdx.x * 128 + wv * 32;
    int node0 = nodeBase + col, node1 = nodeBase + 16 + col;

    f32x4 acc[2][8];
#pragma unroll
    for (int nb = 0; nb < 2; nb++)
#pragma unroll
        for (int f = 0; f < 8; f++) acc[nb][f] = (f32x4)0.f;

    for (int s = 0; s < 4; s++) {
        int k0 = s * 32 + quad * 8;
        float v0[8], v1[8];
#pragma unroll
        for (int j = 0; j < 8; j++) { v0[j] = 0.f; v1[j] = 0.f; }
        if (node0 < N) {
            float4 a = *(const float4*)&A[(size_t)node0 * 128 + k0];
            float4 b = *(const float4*)&A[(size_t)node0 * 128 + k0 + 4];
            v0[0] = a.x; v0[1] = a.y; v0[2] = a.z; v0[3] = a.w;
            v0[4] = b.x; v0[5] = b.y; v0[6] = b.z; v0[7] = b.w;
        }
        if (node1 < N) {
            float4 a = *(const float4*)&A[(size_t)node1 * 128 + k0];
            float4 b = *(const float4*)&A[(size_t)node1 * 128 + k0 + 4];
            v1[0] = a.x; v1[1] = a.y; v1[2] = a.z; v1[3] = a.w;
            v1[4] = b.x; v1[5] = b.y; v1[6] = b.z; v1[7] = b.w;
        }
        bf16x8 bh0, bl0, bh1, bl1;
#pragma unroll
        for (int j = 0; j < 8; j++) {
            ushort h, l;
            split2(v0[j], h, l); bh0[j] = (short)h; bl0[j] = (short)l;
            split2(v1[j], h, l); bh1[j] = (short)h; bl1[j] = (short)l;
        }
#pragma unroll
        for (int f = 0; f < 8; f++) {
            bf16x8 wh = *(const bf16x8*)&Whi_s[f * 16 + col][k0];
            bf16x8 wl = *(const bf16x8*)&Wlo_s[f * 16 + col][k0];
            acc[0][f] = __builtin_amdgcn_mfma_f32_16x16x32_bf16(wh, bh0, acc[0][f], 0, 0, 0);
            acc[1][f] = __builtin_amdgcn_mfma_f32_16x16x32_bf16(wh, bh1, acc[1][f], 0, 0, 0);
            acc[0][f] = __builtin_amdgcn_mfma_f32_16x16x32_bf16(wl, bh0, acc[0][f], 0, 0, 0);
            acc[1][f] = __builtin_amdgcn_mfma_f32_16x16x32_bf16(wl, bh1, acc[1][f], 0, 0, 0);
            acc[0][f] = __builtin_amdgcn_mfma_f32_16x16x32_bf16(wh, bl0, acc[0][f], 0, 0, 0);
            acc[1][f] = __builtin_amdgcn_mfma_f32_16x16x32_bf16(wh, bl1, acc[1][f], 0, 0, 0);
        }
    }
#pragma unroll
    for (int nb = 0; nb < 2; nb++) {
        int node = nodeBase + nb * 16 + col;
        if (node >= N) continue;
        float d = disq[node];
#pragma unroll
        for (int f = 0; f < 8; f++) {
            f32x4 a = acc[nb][f];
            uint2 u;
            u.x = bf16pack(a[0] * d, a[1] * d);
            u.y = bf16pack(a[2] * d, a[3] * d);
            *(uint2*)&Cout[(size_t)node * 64 + f * 8 + quad * 2] = u;
        }
    }
}

// ---- MFMA GEMM, bf16 A (layers 1-4): no A split, 2 MFMAs/frag. ----
template <bool BF16OUT>
__global__ __launch_bounds__(256) void k_gemm_b16A(const unsigned* __restrict__ Ab,
                                                   const ushort* __restrict__ WThi,
                                                   const ushort* __restrict__ WTlo,
                                                   const float* __restrict__ bias,
                                                   const float* __restrict__ disq,
                                                   void* __restrict__ Cout, int N) {
    __shared__ ushort Whi_s[128][136];
    __shared__ ushort Wlo_s[128][136];
    int tid = threadIdx.x;
#pragma unroll
    for (int r = 0; r < 8; r++) {
        int n  = r * 16 + (tid >> 4);
        int kq = (tid & 15) * 8;
        *(uint4*)&Whi_s[n][kq] = *(const uint4*)&WThi[n * 128 + kq];
        *(uint4*)&Wlo_s[n][kq] = *(const uint4*)&WTlo[n * 128 + kq];
    }
    __syncthreads();

    int wv = tid >> 6, ln = tid & 63;
    int quad = ln >> 4, col = ln & 15;
    int nodeBase = blockIdx.x * 128 + wv * 32;
    int node0 = nodeBase + col, node1 = nodeBase + 16 + col;

    f32x4 acc[2][8];
#pragma unroll
    for (int nb = 0; nb < 2; nb++)
#pragma unroll
        for (int f = 0; f < 8; f++) acc[nb][f] = (f32x4)0.f;

    for (int s = 0; s < 4; s++) {
        int k0 = s * 32 + quad * 8;     // element offset
        int kw = s * 16 + quad * 4;     // word offset (2 bf16/word)
        bf16x8 b0 = (bf16x8)(short)0, b1 = (bf16x8)(short)0;
        if (node0 < N) b0 = *(const bf16x8*)&Ab[(size_t)node0 * 64 + kw];
        if (node1 < N) b1 = *(const bf16x8*)&Ab[(size_t)node1 * 64 + kw];
#pragma unroll
        for (int f = 0; f < 8; f++) {
            bf16x8 wh = *(const bf16x8*)&Whi_s[f * 16 + col][k0];
            bf16x8 wl = *(const bf16x8*)&Wlo_s[f * 16 + col][k0];
            acc[0][f] = __builtin_amdgcn_mfma_f32_16x16x32_bf16(wh, b0, acc[0][f], 0, 0, 0);
            acc[1][f] = __builtin_amdgcn_mfma_f32_16x16x32_bf16(wh, b1, acc[1][f], 0, 0, 0);
            acc[0][f] = __builtin_amdgcn_mfma_f32_16x16x32_bf16(wl, b0, acc[0][f], 0, 0, 0);
            acc[1][f] = __builtin_amdgcn_mfma_f32_16x16x32_bf16(wl, b1, acc[1][f], 0, 0, 0);
        }
    }
#pragma unroll
    for (int nb = 0; nb < 2; nb++) {
        int node = nodeBase + nb * 16 + col;
        if (node >= N) continue;
        if (BF16OUT) {
            float d = disq[node];
            unsigned* tb = (unsigned*)Cout;
#pragma unroll
            for (int f = 0; f < 8; f++) {
                f32x4 a = acc[nb][f];
                uint2 u;
                u.x = bf16pack(a[0] * d, a[1] * d);
                u.y = bf16pack(a[2] * d, a[3] * d);
                *(uint2*)&tb[(size_t)node * 64 + f * 8 + quad * 2] = u;
            }
        } else {
            float* C = (float*)Cout;
#pragma unroll
            for (int f = 0; f < 8; f++) {
                int fb = f * 16 + quad * 4;
                float4 bv = *(const float4*)&bias[fb];
                f32x4 a = acc[nb][f];
                float4 o;
                o.x = a[0] + bv.x; o.y = a[1] + bv.y;
                o.z = a[2] + bv.z; o.w = a[3] + bv.w;
                *(float4*)&C[(size_t)node * 128 + fb] = o;
            }
        }
    }
}

// ---- Gather-aggregate: one wave per node, quarter-wave per edge row. ----
// Quarter q handles edges e0+q, e0+q+4, ... Meta loaded directly (same-line
// broadcast across the 16 lanes), rotating 4-slot pipeline overlaps the
// 256B row gathers with expand+FMA. Output packed bf16.
__global__ __launch_bounds__(256) void k_aggregate(const unsigned* __restrict__ tb,
                                                   const int* __restrict__ offsets,
                                                   const uint2* __restrict__ edges,
                                                   const float* __restrict__ disq,
                                                   const float* __restrict__ bias,
                                                   unsigned* __restrict__ outb,
                                                   int N, int relu) {
    int wave = threadIdx.x >> 6;
    int lane = threadIdx.x & 63;
    int node = blockIdx.x * 4 + wave;
    if (node >= N) return;
    int q  = lane >> 4;
    int li = lane & 15;

    int e0 = offsets[node], e1 = offsets[node + 1];
    int deg = e1 - e0;
    float4 acc0 = make_float4(0.f, 0.f, 0.f, 0.f);
    float4 acc1 = make_float4(0.f, 0.f, 0.f, 0.f);

    int eL = e0 + q;                 // this quarter's slot-0 edge
    float cf[4];
    uint4 w[4];
#pragma unroll
    for (int s = 0; s < 4; s++) { cf[s] = 0.f; w[s] = make_uint4(0u, 0u, 0u, 0u); }

#define FETCH(S, II) {                                                     \
        int ii = (II);                                                     \
        bool v = ii < e1;                                                  \
        if (v) {                                                           \
            uint2 m = edges[ii];                                           \
            cf[S] = __uint_as_float(m.y);                                  \
            w[S]  = *(const uint4*)&tb[(size_t)m.x * 64 + li * 4];         \
        } else cf[S] = 0.f;                                                \
    }
#define CONSUME(S) {                                                       \
        float4 a, b; bf16x8_expand(w[S], a, b);                            \
        float c = cf[S];                                                   \
        acc0.x += c * a.x; acc0.y += c * a.y;                              \
        acc0.z += c * a.z; acc0.w += c * a.w;                              \
        acc1.x += c * b.x; acc1.y += c * b.y;                              \
        acc1.z += c * b.z; acc1.w += c * b.w;                              \
    }

    FETCH(0, eL)
    FETCH(1, eL + 4)
    FETCH(2, eL + 8)
    FETCH(3, eL + 12)
    for (int base = 16; base < deg; base += 16) {
        CONSUME(0) FETCH(0, eL + base)
        CONSUME(1) FETCH(1, eL + base + 4)
        CONSUME(2) FETCH(2, eL + base + 8)
        CONSUME(3) FETCH(3, eL + base + 12)
    }
    CONSUME(0) CONSUME(1) CONSUME(2) CONSUME(3)
#undef FETCH
#undef CONSUME

#pragma unroll
    for (int m = 16; m <= 32; m <<= 1) {
        acc0.x += __shfl_xor(acc0.x, m);
        acc0.y += __shfl_xor(acc0.y, m);
        acc0.z += __shfl_xor(acc0.z, m);
        acc0.w += __shfl_xor(acc0.w, m);
        acc1.x += __shfl_xor(acc1.x, m);
        acc1.y += __shfl_xor(acc1.y, m);
        acc1.z += __shfl_xor(acc1.z, m);
        acc1.w += __shfl_xor(acc1.w, m);
    }
    if (q == 0) {
        float d = disq[node];
        uint4 wv = *(const uint4*)&tb[(size_t)node * 64 + li * 4];
        float4 ta, tbv;
        bf16x8_expand(wv, ta, tbv);
        float4 b0 = *(const float4*)&bias[li * 8];
        float4 b1 = *(const float4*)&bias[li * 8 + 4];
        float4 o0, o1;
        o0.x = d * (acc0.x + ta.x) + b0.x;
        o0.y = d * (acc0.y + ta.y) + b0.y;
        o0.z = d * (acc0.z + ta.z) + b0.z;
        o0.w = d * (acc0.w + ta.w) + b0.w;
        o1.x = d * (acc1.x + tbv.x) + b1.x;
        o1.y = d * (acc1.y + tbv.y) + b1.y;
        o1.z = d * (acc1.z + tbv.z) + b1.z;
        o1.w = d * (acc1.w + tbv.w) + b1.w;
        if (relu) {
            o0.x = fmaxf(o0.x, 0.f); o0.y = fmaxf(o0.y, 0.f);
            o0.z = fmaxf(o0.z, 0.f); o0.w = fmaxf(o0.w, 0.f);
            o1.x = fmaxf(o1.x, 0.f); o1.y = fmaxf(o1.y, 0.f);
            o1.z = fmaxf(o1.z, 0.f); o1.w = fmaxf(o1.w, 0.f);
        }
        uint4 u;
        u.x = bf16pack(o0.x, o0.y);
        u.y = bf16pack(o0.z, o0.w);
        u.z = bf16pack(o1.x, o1.y);
        u.w = bf16pack(o1.z, o1.w);
        *(uint4*)&outb[(size_t)node * 64 + li * 4] = u;
    }
}

extern "C" void kernel_launch(void* const* d_in, const int* in_sizes, int n_in,
                              void* d_out, int out_size, void* d_ws, size_t ws_size,
                              hipStream_t stream) {
    const float* x    = (const float*)d_in[0];
    const int*   ei   = (const int*)d_in[1];
    const float* ew   = (const float*)d_in[2];
    const float* Wc[4] = {(const float*)d_in[3], (const float*)d_in[5],
                          (const float*)d_in[7], (const float*)d_in[9]};
    const float* bc[4] = {(const float*)d_in[4], (const float*)d_in[6],
                          (const float*)d_in[8], (const float*)d_in[10]};
    const float* Wout = (const float*)d_in[11];
    const float* bout = (const float*)d_in[12];

    const int N = in_sizes[0] / 128;
    const int E = in_sizes[2];
    const int* row = ei;
    const int* col = ei + E;

    const int K     = (N + 255) >> 8;
    const int B1    = 256;
    const int chunk = (E + B1 - 1) / B1;
    const int nScan = K * B1;

    size_t off = 0;
    char* base = (char*)d_ws;
    auto alloc = [&](size_t bytes) -> void* {
        void* p = base + off;
        off += (bytes + 255) & ~(size_t)255;
        return p;
    };
    float*    disq     = (float*)alloc((size_t)N * 4);
    int*      offsets  = (int*)alloc((size_t)(N + 1) * 4);
    int*      hist     = (int*)alloc((size_t)nScan * 4);
    int*      binBase  = (int*)alloc((size_t)(nScan + 1) * 4);
    int*      partials = (int*)alloc(1024 * 4);
    int*      blockOff = (int*)alloc(1024 * 4);
    ushort*   WThi     = (ushort*)alloc((size_t)5 * 16384 * 2);
    ushort*   WTlo     = (ushort*)alloc((size_t)5 * 16384 * 2);
    uint2*    etmp     = (uint2*)alloc((size_t)E * 8);
    uint2*    edges    = (uint2*)alloc((size_t)E * 8);
    unsigned* hb       = (unsigned*)alloc((size_t)N * 64 * 4);   // bf16 h
    unsigned* tb       = (unsigned*)alloc((size_t)N * 64 * 4);   // bf16 t'

    const int BG  = (N + 127) / 128;
    const int BA  = (N + 3) / 4;
    const int NBs = (nScan + SCAN_CHUNK - 1) / SCAN_CHUNK;

    // Weight prep + CSR build (no global atomics)
    k_prepw<<<5, 256, 0, stream>>>(Wc[0], Wc[1], Wc[2], Wc[3], Wout, WThi, WTlo);
    k_hist<<<B1, 256, 0, stream>>>(col, hist, E, K, B1, chunk);
    k_scan_part<<<NBs, 256, 0, stream>>>(hist, partials, nScan);
    k_scan_top<<<1, 1024, 0, stream>>>(partials, blockOff, binBase, NBs, nScan);
    k_scan_out<<<NBs, 256, 0, stream>>>(hist, blockOff, binBase, nScan);
    k_scatter<<<B1, 256, 0, stream>>>(row, col, ew, binBase, etmp, E, K, B1, chunk);
    k_bucket<<<K, 256, 0, stream>>>(etmp, binBase, edges, offsets, disq, N, K, B1);

    // Layers (GEMM -> aggregate); h kept in bf16 from layer 1 on
    k_gemm_f32A<<<BG, 256, 0, stream>>>(x, WThi, WTlo, disq, tb, N);
    k_aggregate<<<BA, 256, 0, stream>>>(tb, offsets, edges, disq, bc[0], hb, N, 1);
    k_gemm_b16A<true><<<BG, 256, 0, stream>>>(hb, WThi + 16384, WTlo + 16384, nullptr, disq, tb, N);
    k_aggregate<<<BA, 256, 0, stream>>>(tb, offsets, edges, disq, bc[1], hb, N, 1);
    k_gemm_b16A<true><<<BG, 256, 0, stream>>>(hb, WThi + 32768, WTlo + 32768, nullptr, disq, tb, N);
    k_aggregate<<<BA, 256, 0, stream>>>(tb, offsets, edges, disq, bc[2], hb, N, 1);
    k_gemm_b16A<true><<<BG, 256, 0, stream>>>(hb, WThi + 49152, WTlo + 49152, nullptr, disq, tb, N);
    k_aggregate<<<BA, 256, 0, stream>>>(tb, offsets, edges, disq, bc[3], hb, N, 0);
    // Output projection (fp32 + bias)
    k_gemm_b16A<false><<<BG, 256, 0, stream>>>(hb, WThi + 65536, WTlo + 65536, bout, nullptr, d_out, N);
}